// Round 6
// baseline (449.725 us; speedup 1.0000x reference)
//
#include <hip/hip_runtime.h>
#include <hip/hip_bf16.h>
#include <math.h>

#define NN 65536
#define EE 262144

typedef unsigned short u16;
typedef unsigned int u32;
typedef __attribute__((ext_vector_type(8))) short bf16x8;
typedef __attribute__((ext_vector_type(4))) float f32x4;
typedef __attribute__((ext_vector_type(16))) float f32x16;

__device__ __forceinline__ float bfu2f(u16 u){ return __uint_as_float(((u32)u)<<16); }
__device__ __forceinline__ u16 f2bfu(float f){
  u32 x = __float_as_uint(f);
  return (u16)((x + 0x7fffu + ((x>>16)&1u)) >> 16);
}
__device__ __forceinline__ float lrelu(float x){ return x>0.f ? x : 0.2f*x; }
__device__ __forceinline__ float fexp(float x){ return __expf(x); }

// ---- weight convert + transpose: B [K][N] f32 -> Bt [N][K] bf16
__global__ void k_cvtT(const float* __restrict__ B, u16* __restrict__ Bt, int K, int N){
  int idx = blockIdx.x*256+threadIdx.x;
  if (idx < K*N){ int k = idx/N, n = idx - k*N; Bt[n*K+k] = f2bfu(B[idx]); }
}

// ---- node features f32 -> bf16 (vectorized)
__global__ void k_cvtn(const float* __restrict__ nf, u16* __restrict__ nfb){
  int i = (blockIdx.x*256+threadIdx.x)*4;
  float4 v = *(const float4*)(nf + i);
  ushort4 o; o.x=f2bfu(v.x); o.y=f2bfu(v.y); o.z=f2bfu(v.z); o.w=f2bfu(v.w);
  *(ushort4*)(nfb + i) = o;
}

// ---- BN1 stats over z1 = poses@w1+b1 (cols=64)
__global__ void k_bn1_stats(const float* __restrict__ poses, const float* __restrict__ w1,
                            const float* __restrict__ b1, float* __restrict__ sum1, float* __restrict__ sq1){
  int wave = (blockIdx.x*blockDim.x + threadIdx.x)>>6;
  int c = threadIdx.x & 63;
  float wc[6];
#pragma unroll
  for (int j=0;j<6;++j) wc[j] = w1[j*64+c];
  float bb = b1[c];
  float s=0.f,q=0.f;
  int e0 = wave*(EE/1024);
  for (int e=e0;e<e0+(EE/1024);++e){
    float z = bb;
#pragma unroll
    for (int j=0;j<6;++j) z = fmaf(poses[e*6+j], wc[j], z);
    s += z; q += z*z;
  }
  unsafeAtomicAdd(&sum1[c], s);
  unsafeAtomicAdd(&sq1[c], q);
}

__global__ void k_bn_fin(const float* __restrict__ sum, const float* __restrict__ sq,
                         const float* __restrict__ g, const float* __restrict__ be,
                         const float* __restrict__ bias0,
                         float* __restrict__ a, float* __restrict__ cc, int cols){
  int c = threadIdx.x;
  if (c<cols){
    float mu = sum[c]*(1.f/EE);
    float var = sq[c]*(1.f/EE) - mu*mu;
    float istd = rsqrtf(var + 1e-5f);
    float ac = istd*g[c];
    a[c] = ac;
    float cv = be[c] - mu*ac;
    if (bias0) cv += bias0[c]*ac;
    cc[c] = cv;
  }
}

// ---- reduce per-block BN2 partials: psum/psq [4096][128] -> part2 [32][256]
__global__ void k_red2(const float* __restrict__ psum, const float* __restrict__ psq,
                       float* __restrict__ part2){
  int t = threadIdx.x;
  int b0 = blockIdx.x*128;
  float s = 0.f;
  if (t < 128){
    for (int k=0;k<128;++k) s += psum[(size_t)(b0+k)*128 + t];
  } else {
    int c = t-128;
    for (int k=0;k<128;++k) s += psq[(size_t)(b0+k)*128 + c];
  }
  part2[blockIdx.x*256 + t] = s;
}

__global__ void k_bn_fin2(const float* __restrict__ part2,
                          const float* __restrict__ g, const float* __restrict__ be,
                          const float* __restrict__ bias0,
                          float* __restrict__ a, float* __restrict__ cc){
  int c = threadIdx.x;
  if (c<128){
    float s=0.f,q=0.f;
    for (int k=0;k<32;++k){ s += part2[k*256+c]; q += part2[k*256+128+c]; }
    float mu = s*(1.f/EE);
    float var = q*(1.f/EE) - mu*mu;
    float istd = rsqrtf(var + 1e-5f);
    float ac = istd*g[c];
    a[c] = ac;
    cc[c] = be[c] - mu*ac + bias0[c]*ac;
  }
}

// ---- h1 = relu(bn1(z1)) stored bf16 [E,64]
__global__ void k_h1(const float* __restrict__ poses, const float* __restrict__ w1, const float* __restrict__ b1,
                     const float* __restrict__ a1, const float* __restrict__ c1, u16* __restrict__ h1){
  int idx = blockIdx.x*256+threadIdx.x;
  int e = idx>>6, c = idx&63;
  float z = b1[c];
#pragma unroll
  for (int j=0;j<6;++j) z = fmaf(poses[e*6+j], w1[j*64+c], z);
  float h = z*a1[c]+c1[c];
  h1[idx] = f2bfu(h>0.f?h:0.f);
}

// ============ MFMA GEMM: C[64x128 tile] = A[M,K]bf16 @ Bt[N,K]bf16^T ============
// EPI: 2 BN partial stats | 6 relu(acc*a+c) bf16 | 7 fused gamma+beta FiLM (coalesced nfsel)
template<int EPI>
__launch_bounds__(256)
__global__ void k_mm(const u16* __restrict__ A, const u16* __restrict__ Bt,
                     const u16* __restrict__ Bt2,
                     int K, int lda, int ldbt, int ldc,
                     u16* __restrict__ outb,
                     const float* __restrict__ bias, const float* __restrict__ bias2,
                     float* __restrict__ ssum, float* __restrict__ ssq,
                     const float* __restrict__ gb,
                     const float* __restrict__ bb, const u16* __restrict__ nfselb,
                     const int* __restrict__ lastE){
  const int m0 = blockIdx.x*64, n0 = blockIdx.y*128;
  const int t = threadIdx.x;
  const int lane = t & 63, wv = t>>6;
  const int wr = wv>>1, wc = wv&1;
  __shared__ u16 Als[64*64];
  __shared__ u16 Bls[128*64];
  __shared__ u16 B2ls[EPI==7 ? 128*64 : 8];
  __shared__ float epiS[128][2];
  __shared__ float epiD[128][2];
  f32x4 acc[2][4];
  f32x4 acc2[2][4];
#pragma unroll
  for (int i=0;i<2;++i)
#pragma unroll
    for (int j=0;j<4;++j){ acc[i][j] = (f32x4){0.f,0.f,0.f,0.f}; acc2[i][j] = (f32x4){0.f,0.f,0.f,0.f}; }

  for (int k0=0;k0<K;k0+=64){
    constexpr int NS = (EPI==7) ? 10 : 6;
#pragma unroll
    for (int c=0;c<NS;++c){
      int gc = c*256 + t;
      if (gc < 512){
        int row = gc>>3, ch = gc&7;
        int sw = ((row<<3)|ch) ^ (row&7);
        *(uint4*)(Als + sw*8) = *(const uint4*)(A + (size_t)(m0+row)*lda + k0 + ch*8);
      } else if (gc < 1536){
        int g2 = gc - 512;
        int row = g2>>3, ch = g2&7;
        int sw = ((row<<3)|ch) ^ (row&7);
        *(uint4*)(Bls + sw*8) = *(const uint4*)(Bt + (size_t)(n0+row)*ldbt + k0 + ch*8);
      } else if constexpr (EPI==7){
        int g2 = gc - 1536;
        int row = g2>>3, ch = g2&7;
        int sw = ((row<<3)|ch) ^ (row&7);
        *(uint4*)(B2ls + sw*8) = *(const uint4*)(Bt2 + (size_t)(n0+row)*ldbt + k0 + ch*8);
      }
    }
    __syncthreads();
#pragma unroll
    for (int kk=0;kk<2;++kk){
      bf16x8 af[2], bfr[4];
      int ch = kk*4 + (lane>>4);
#pragma unroll
      for (int i=0;i<2;++i){
        int row = wr*32 + i*16 + (lane&15);
        int sw = ((row<<3)|ch) ^ (row&7);
        af[i] = *(const bf16x8*)(Als + sw*8);
      }
#pragma unroll
      for (int j=0;j<4;++j){
        int rowb = wc*64 + j*16 + (lane&15);
        int swb = ((rowb<<3)|ch) ^ (rowb&7);
        bfr[j] = *(const bf16x8*)(Bls + swb*8);
      }
#pragma unroll
      for (int i=0;i<2;++i)
#pragma unroll
        for (int j=0;j<4;++j)
          acc[i][j] = __builtin_amdgcn_mfma_f32_16x16x32_bf16(af[i], bfr[j], acc[i][j], 0,0,0);
      if constexpr (EPI==7){
        bf16x8 bf2[4];
#pragma unroll
        for (int j=0;j<4;++j){
          int rowb = wc*64 + j*16 + (lane&15);
          int swb = ((rowb<<3)|ch) ^ (rowb&7);
          bf2[j] = *(const bf16x8*)(B2ls + swb*8);
        }
#pragma unroll
        for (int i=0;i<2;++i)
#pragma unroll
          for (int j=0;j<4;++j)
            acc2[i][j] = __builtin_amdgcn_mfma_f32_16x16x32_bf16(af[i], bf2[j], acc2[i][j], 0,0,0);
      }
    }
    __syncthreads();
  }

  int cbase = wc*64 + (lane&15);

  if constexpr (EPI==6){
    float av[4], cv[4];
#pragma unroll
    for (int j=0;j<4;++j){ av[j]=bias[cbase+j*16]; cv[j]=bias2[cbase+j*16]; }
#pragma unroll
    for (int i=0;i<2;++i)
#pragma unroll
      for (int r=0;r<4;++r){
        int row = m0 + wr*32 + i*16 + ((lane>>4)<<2) + r;
#pragma unroll
        for (int j=0;j<4;++j){
          float h = fmaf(acc[i][j][r], av[j], cv[j]);
          outb[(size_t)row*128 + cbase + j*16] = f2bfu(h>0.f?h:0.f);
        }
      }
  } else if constexpr (EPI==2){
    float bv[4];
#pragma unroll
    for (int j=0;j<4;++j) bv[j]=bias[cbase+j*16];
    float s[4]={0,0,0,0}, q[4]={0,0,0,0};
#pragma unroll
    for (int i=0;i<2;++i)
#pragma unroll
      for (int j=0;j<4;++j)
#pragma unroll
        for (int r=0;r<4;++r){ float z = acc[i][j][r]+bv[j]; s[j]+=z; q[j]+=z*z; }
#pragma unroll
    for (int j=0;j<4;++j){
      float ss=s[j], qq=q[j];
      ss += __shfl_xor(ss,16); ss += __shfl_xor(ss,32);
      qq += __shfl_xor(qq,16); qq += __shfl_xor(qq,32);
      if (lane<16){
        epiS[wc*64+j*16+lane][wr] = ss;
        epiD[wc*64+j*16+lane][wr] = qq;
      }
    }
    __syncthreads();
    if (t<128){
      ssum[(size_t)blockIdx.x*128 + t] = epiS[t][0]+epiS[t][1];
      ssq[(size_t)blockIdx.x*128 + t]  = epiD[t][0]+epiD[t][1];
    }
  } else if constexpr (EPI==7){
    float gbv[4], bbv[4];
#pragma unroll
    for (int j=0;j<4;++j){ gbv[j]=gb[cbase+j*16]; bbv[j]=bb[cbase+j*16]; }
#pragma unroll
    for (int i=0;i<2;++i)
#pragma unroll
      for (int r=0;r<4;++r){
        int n = m0 + wr*32 + i*16 + ((lane>>4)<<2) + r;
        int le = lastE[n];
#pragma unroll
        for (int j=0;j<4;++j){
          int c = cbase + j*16;
          float nv = bfu2f(nfselb[(size_t)n*128+c]);
          float res;
          if (le>=0){
            float gp = acc[i][j][r] + gbv[j];
            float gam = 2.f/(1.f+fexp(-gp));
            res = fmaf(gam, nv, acc2[i][j][r] + bbv[j]);
          } else res = nv;
          outb[(size_t)n*128+c] = f2bfu(res);
        }
      }
  }
}

// ============ fused GAT1 head-projection + GAT2 GEMM — R3 schedule, 32x32 MFMA ============
// R5 post-mortem: bigger tiles with more waves lose (fewer independent blocks, 16-wave
// barriers). Reverting to R3's proven geometry (BM=64, 512 thr, 8 waves, 33KB LDS,
// 4 blocks/CU) and instead halving the per-phase instruction stream: each wave computes
// ONE 32x32 tile via mfma_f32_32x32x16_bf16. Per wave per head: ds_read_b128 40->16,
// MFMA 32->16 (same FLOPs at the higher 32x32 rate), address VALU ~halves.
// acc1+acc2 = 2x f32x16 = 32 regs, same proven no-spill budget. Staging byte-identical R3.
// Fragment layouts: A/B row=lane&31, k=(lane>>5)*8+j (mirrors proven 16x16 pattern);
// C/D col=lane&31, row=(reg&3)+8*(reg>>2)+4*(lane>>5) (HW-verified).
__launch_bounds__(512)
__global__ void k_proj(const u16* __restrict__ aggH, const u16* __restrict__ g1wt,
                       const u16* __restrict__ g2wt, const float* __restrict__ g1b,
                       const float* __restrict__ asv, const float* __restrict__ adv,
                       u16* __restrict__ xw2b, float* __restrict__ als2, float* __restrict__ ald2){
  const int m0 = blockIdx.x*64;
  const int t = threadIdx.x, lane = t&63, wv = t>>6;
  const int wr = wv>>2, wc = wv&3;          // wr: 0..1 (32-row strip), wc: 0..3 (32-col strip)
  __shared__ u16 ATls[64*128];   // 16KB union: A [64][8ch] per K-panel (8KB) / Tls [64][16ch]
  __shared__ u16 Wls[128*64];    // 16KB: weight K-panel [128 N][8 ch]
  __shared__ float epiS[64][4];
  __shared__ float epiD[64][4];
  const int col  = wc*32 + (lane&31);       // this lane's output column (0..127)
  const int arow = wr*32 + (lane&31);       // this lane's A/T row (0..63)
  const int kg   = lane>>5;                 // K-group: k-offset 8*kg within 16-wide K step
  f32x16 acc2;
#pragma unroll
  for (int r=0;r<16;++r) acc2[r]=0.f;

  for (int hh=0; hh<8; ++hh){
    f32x16 acc1;
#pragma unroll
    for (int r=0;r<16;++r) acc1[r]=0.f;

    // ---- stage 1: acc1 = aggH_hh[64x128] @ W1_hh^T, two K-panels of 64 (R3 staging)
    for (int k0=0;k0<128;k0+=64){
#pragma unroll
      for (int c=0;c<3;++c){
        int gc = c*512 + t;
        if (gc < 512){
          int row = gc>>3, ch = gc&7;
          int sw = ((row<<3)|ch) ^ (row&7);
          *(uint4*)(ATls + sw*8) = *(const uint4*)(aggH + (size_t)(m0+row)*1024 + hh*128 + k0 + ch*8);
        } else {
          int g2 = gc - 512;
          int row = g2>>3, ch = g2&7;
          int sw = ((row<<3)|ch) ^ (row&7);
          *(uint4*)(Wls + sw*8) = *(const uint4*)(g1wt + (size_t)(hh*128+row)*128 + k0 + ch*8);
        }
      }
      __syncthreads();
#pragma unroll
      for (int m=0;m<4;++m){
        int ch = m*2 + kg;
        int sw = ((arow<<3)|ch) ^ (arow&7);
        bf16x8 af = *(const bf16x8*)(ATls + sw*8);
        int swb = ((col<<3)|ch) ^ (col&7);
        bf16x8 bf = *(const bf16x8*)(Wls + swb*8);
        acc1 = __builtin_amdgcn_mfma_f32_32x32x16_bf16(af, bf, acc1, 0,0,0);
      }
      __syncthreads();   // A/W1 reads complete -> ATls reusable as Tls
    }
    // ---- T = ELU(acc1 + b1) -> ATls as Tls [64][128], 16-chunk swizzle
    {
      float bv = g1b[hh*128 + col];
#pragma unroll
      for (int r=0;r<16;++r){
        int mrow = wr*32 + (r&3) + 8*(r>>2) + 4*kg;
        float v = acc1[r] + bv;
        v = v>0.f ? v : fexp(v)-1.f;
        int sw = ((mrow<<4)|(col>>3)) ^ (mrow&7);
        ATls[sw*8 + (col&7)] = f2bfu(v);
      }
    }
    // ---- stage 2: acc2 += T[64x128] @ W2_hh^T, two K-panels of 64
    for (int k0=0;k0<128;k0+=64){
#pragma unroll
      for (int c=0;c<2;++c){
        int g2 = c*512 + t;
        int row = g2>>3, ch = g2&7;
        int sw = ((row<<3)|ch) ^ (row&7);
        *(uint4*)(Wls + sw*8) = *(const uint4*)(g2wt + (size_t)row*1024 + hh*128 + k0 + ch*8);
      }
      __syncthreads();   // covers T-writes + W2 staging
#pragma unroll
      for (int m=0;m<4;++m){
        int chk = (k0>>3) + m*2 + kg;
        int sw = ((arow<<4)|chk) ^ (arow&7);
        bf16x8 af = *(const bf16x8*)(ATls + sw*8);
        int swb = ((col<<3)|(m*2+kg)) ^ (col&7);
        bf16x8 bf = *(const bf16x8*)(Wls + swb*8);
        acc2 = __builtin_amdgcn_mfma_f32_32x32x16_bf16(af, bf, acc2, 0,0,0);
      }
      __syncthreads();   // Tls/Wls reads done -> next head's staging safe
    }
  }
  // ---- epilogue: xw2b store + fused als2/ald2 (per-row 32-col shfl reduce)
  float av = asv[col], dvv = adv[col];
#pragma unroll
  for (int r=0;r<16;++r){
    int lr = wr*32 + (r&3) + 8*(r>>2) + 4*kg;
    float v = acc2[r];
    xw2b[(size_t)(m0+lr)*128 + col] = f2bfu(v);
    float s = v*av, d = v*dvv;
#pragma unroll
    for (int o=1;o<32;o<<=1){ s += __shfl_xor(s,o); d += __shfl_xor(d,o); }
    if ((lane&31)==0){ epiS[lr][wc]=s; epiD[lr][wc]=d; }
  }
  __syncthreads();
  if (t<64){
    als2[m0+t] = epiS[t][0]+epiS[t][1]+epiS[t][2]+epiS[t][3];
    ald2[m0+t] = epiD[t][0]+epiD[t][1]+epiD[t][2]+epiD[t][3];
  }
}

// ---- last-edge-wins + degree (fused) + CSR build
__global__ void k_lastdeg(const int* __restrict__ dst, int* __restrict__ lastE, int* __restrict__ deg){
  int e = blockIdx.x*256+threadIdx.x;
  int d = dst[e];
  atomicMax(&lastE[d], e);
  atomicAdd(&deg[d], 1);
}
__global__ void k_blocksum(const int* __restrict__ deg, int* __restrict__ bsum){
  __shared__ int s[256];
  int t = threadIdx.x;
  s[t] = deg[blockIdx.x*256+t];
  __syncthreads();
  for (int o=128;o>0;o>>=1){ if (t<o) s[t]+=s[t+o]; __syncthreads(); }
  if (!t) bsum[blockIdx.x]=s[0];
}
__global__ void k_scanb(int* __restrict__ bsum){
  __shared__ int s[256];
  int t=threadIdx.x;
  s[t]=bsum[t]; __syncthreads();
  for (int o=1;o<256;o<<=1){
    int v = s[t];
    if (t>=o) v += s[t-o];
    __syncthreads(); s[t]=v; __syncthreads();
  }
  bsum[t] = t ? s[t-1] : 0;
}
__global__ void k_indptr(const int* __restrict__ deg, const int* __restrict__ bsum, int* __restrict__ indptr){
  __shared__ int s[256];
  int t=threadIdx.x; int g=blockIdx.x*256+t;
  int d = deg[g];
  s[t]=d; __syncthreads();
  for (int o=1;o<256;o<<=1){
    int v = s[t];
    if (t>=o) v += s[t-o];
    __syncthreads(); s[t]=v; __syncthreads();
  }
  indptr[g] = bsum[blockIdx.x] + s[t] - d;
  if (g==NN-1) indptr[NN]=EE;
}
__global__ void k_fill(const int* __restrict__ srcA, const int* __restrict__ dstA,
                       const int* __restrict__ indptr, int* __restrict__ cursor, int* __restrict__ slist){
  int e = blockIdx.x*256+threadIdx.x;
  int d = dstA[e];
  int p = atomicAdd(&cursor[d],1);
  slist[indptr[d]+p] = srcA[e];
}

// ---- fused gather: h1sel [N,64]b + nfselb [N,128]b in one pass over lastE/srcA
__global__ void k_gsel(const u16* __restrict__ h1, const u16* __restrict__ nodefb,
                       const int* __restrict__ lastE, const int* __restrict__ srcA,
                       u16* __restrict__ h1sel, u16* __restrict__ nfselb){
  int g = blockIdx.x*256+threadIdx.x;
  int n = g>>4, ch = g&15;
  int le = lastE[n];
  int src = (le>=0) ? srcA[le] : n;
  *(uint4*)(nfselb + (size_t)n*128 + ch*8) = *(const uint4*)(nodefb + (size_t)src*128 + ch*8);
  if (ch < 8){
    uint4 v = make_uint4(0,0,0,0);
    if (le>=0) v = *(const uint4*)(h1 + (size_t)le*64 + ch*8);
    *(uint4*)(h1sel + (size_t)n*64 + ch*8) = v;
  }
}

// ---- vas1/vad1 precontraction -> bf16 V^T [16][128]
__global__ void k_vprep(const float* __restrict__ g1w, const float* __restrict__ as_,
                        const float* __restrict__ ad_, u16* __restrict__ vtb){
  int gid = blockIdx.x*256+threadIdx.x;
  if (gid<1024){
    int h = gid>>7, k = gid&127;
    float s=0.f,d=0.f;
    for (int cc=0;cc<128;++cc){
      float wv = g1w[(size_t)k*1024 + h*128+cc];
      s=fmaf(wv,as_[h*128+cc],s); d=fmaf(wv,ad_[h*128+cc],d);
    }
    vtb[h*128+k] = f2bfu(s);
    vtb[(h+8)*128+k] = f2bfu(d);
  }
}

// ---- als1/ald1 [N,8] via skinny MFMA: [N,16] = encb @ V^T
__launch_bounds__(256)
__global__ void k_als1mm(const u16* __restrict__ encb, const u16* __restrict__ vtb,
                         float* __restrict__ als, float* __restrict__ ald){
  int t = threadIdx.x, lane = t&63, wv = t>>6;
  int m0 = blockIdx.x*64 + wv*16;
  f32x4 acc = (f32x4){0.f,0.f,0.f,0.f};
  const u16* arow = encb + (size_t)(m0 + (lane&15))*128;
  const u16* brow = vtb + (lane&15)*128;
  int ko = (lane>>4)*8;
#pragma unroll
  for (int k0=0;k0<128;k0+=32){
    bf16x8 af = *(const bf16x8*)(arow + k0 + ko);
    bf16x8 bf = *(const bf16x8*)(brow + k0 + ko);
    acc = __builtin_amdgcn_mfma_f32_16x16x32_bf16(af, bf, acc, 0,0,0);
  }
  int o = lane&15;
#pragma unroll
  for (int r=0;r<4;++r){
    int row = m0 + ((lane>>4)<<2) + r;
    if (o<8) als[(size_t)row*8+o] = acc[r];
    else     ald[(size_t)row*8+(o-8)] = acc[r];
  }
}

// ---- CSR node-parallel softmax, GAT1: 1 wave/node, lanes = 8 edges x 8 heads
__launch_bounds__(256)
__global__ void k_soft1(const int* __restrict__ slist, const int* __restrict__ indptr,
                        const float* __restrict__ als, const float* __restrict__ ald,
                        float* __restrict__ wcsr, float* __restrict__ den1, float* __restrict__ wself1){
  int t = threadIdx.x;
  int n = blockIdx.x*4 + (t>>6);
  int lane = t&63;
  int ei = lane>>3, h = lane&7;
  int p0 = indptr[n], p1 = indptr[n+1];
  float adh = ald[(size_t)n*8+h];
  float selfsc = lrelu(als[(size_t)n*8+h] + adh);
  float m = selfsc;
  for (int p=p0+ei; p<p1; p+=8){
    int s = slist[p];
    m = fmaxf(m, lrelu(als[(size_t)s*8+h] + adh));
  }
  m = fmaxf(m, __shfl_xor(m,8));
  m = fmaxf(m, __shfl_xor(m,16));
  m = fmaxf(m, __shfl_xor(m,32));
  float ws = fexp(selfsc - m);
  float den = (ei==0) ? ws : 0.f;
  for (int p=p0+ei; p<p1; p+=8){
    int s = slist[p];
    float w = fexp(lrelu(als[(size_t)s*8+h] + adh) - m);
    wcsr[(size_t)p*8+h] = w;
    den += w;
  }
  den += __shfl_xor(den,8);
  den += __shfl_xor(den,16);
  den += __shfl_xor(den,32);
  if (ei==0){
    den1[(size_t)n*8+h] = den;
    wself1[(size_t)n*8+h] = ws;
  }
}

// ---- CSR node-parallel softmax, GAT2: 16 lanes/node
__launch_bounds__(256)
__global__ void k_soft2(const int* __restrict__ slist, const int* __restrict__ indptr,
                        const float* __restrict__ als, const float* __restrict__ ald,
                        float* __restrict__ wcsr, float* __restrict__ den2, float* __restrict__ wself2){
  int t = threadIdx.x;
  int n = blockIdx.x*16 + (t>>4);
  int l = t&15;
  int p0 = indptr[n], p1 = indptr[n+1];
  float adh = ald[n];
  float selfsc = lrelu(als[n] + adh);
  float m = selfsc;
  for (int p=p0+l; p<p1; p+=16)
    m = fmaxf(m, lrelu(als[slist[p]] + adh));
  m = fmaxf(m, __shfl_xor(m,1));
  m = fmaxf(m, __shfl_xor(m,2));
  m = fmaxf(m, __shfl_xor(m,4));
  m = fmaxf(m, __shfl_xor(m,8));
  float ws = fexp(selfsc - m);
  float den = (l==0) ? ws : 0.f;
  for (int p=p0+l; p<p1; p+=16){
    float w = fexp(lrelu(als[slist[p]] + adh) - m);
    wcsr[p] = w;
    den += w;
  }
  den += __shfl_xor(den,1);
  den += __shfl_xor(den,2);
  den += __shfl_xor(den,4);
  den += __shfl_xor(den,8);
  if (l==0){ den2[n] = den; wself2[n] = ws; }
}

// ---- GAT1 enc-space aggregation, single pass, all 8 heads per enc-row load
__launch_bounds__(256)
__global__ void k_agg1(const u16* __restrict__ encb, const float* __restrict__ wcsr,
                       const float* __restrict__ den1, const float* __restrict__ wself1,
                       const int* __restrict__ slist, const int* __restrict__ indptr,
                       u16* __restrict__ aggH){
  int t = threadIdx.x;
  int n = blockIdx.x*4 + (t>>6);
  int lane = t&63;
  int c0 = lane*2;
  int p0 = indptr[n], p1 = indptr[n+1];
  float a0[8], a1[8];
  {
    ushort2 u = *(const ushort2*)(encb + (size_t)n*128 + c0);
    float x0 = bfu2f(u.x), x1 = bfu2f(u.y);
#pragma unroll
    for (int h=0;h<8;++h){
      float ws = wself1[(size_t)n*8 + h];
      a0[h] = ws*x0; a1[h] = ws*x1;
    }
  }
  for (int p=p0; p<p1; ++p){
    int s = slist[p];
    float4 w0 = *(const float4*)(wcsr + (size_t)p*8);
    float4 w1 = *(const float4*)(wcsr + (size_t)p*8 + 4);
    ushort2 u = *(const ushort2*)(encb + (size_t)s*128 + c0);
    float x0 = bfu2f(u.x), x1 = bfu2f(u.y);
    a0[0]=fmaf(w0.x,x0,a0[0]); a1[0]=fmaf(w0.x,x1,a1[0]);
    a0[1]=fmaf(w0.y,x0,a0[1]); a1[1]=fmaf(w0.y,x1,a1[1]);
    a0[2]=fmaf(w0.z,x0,a0[2]); a1[2]=fmaf(w0.z,x1,a1[2]);
    a0[3]=fmaf(w0.w,x0,a0[3]); a1[3]=fmaf(w0.w,x1,a1[3]);
    a0[4]=fmaf(w1.x,x0,a0[4]); a1[4]=fmaf(w1.x,x1,a1[4]);
    a0[5]=fmaf(w1.y,x0,a0[5]); a1[5]=fmaf(w1.y,x1,a1[5]);
    a0[6]=fmaf(w1.z,x0,a0[6]); a1[6]=fmaf(w1.z,x1,a1[6]);
    a0[7]=fmaf(w1.w,x0,a0[7]); a1[7]=fmaf(w1.w,x1,a1[7]);
  }
#pragma unroll
  for (int h=0;h<8;++h){
    float rr = 1.f/den1[(size_t)n*8 + h];
    u32 pk = (u32)f2bfu(a0[h]*rr) | ((u32)f2bfu(a1[h]*rr)<<16);
    *(u32*)(aggH + (size_t)n*1024 + h*128 + c0) = pk;
  }
}

// ---- GAT2 aggregation: pure weighted gather of bf16 xw2
__launch_bounds__(128)
__global__ void k_gat2(const u16* __restrict__ xw2b, const float* __restrict__ wcsr,
                       const float* __restrict__ den2, const float* __restrict__ wself2,
                       const int* __restrict__ slist, const int* __restrict__ indptr,
                       const float* __restrict__ g2b, float* __restrict__ out){
  int n = blockIdx.x, c = threadIdx.x;
  int p0 = indptr[n], p1 = indptr[n+1];
  float acc = wself2[n]*bfu2f(xw2b[(size_t)n*128+c]);
  int p = p0;
  for (; p+4<=p1; p+=4){
    int s0=slist[p], s1=slist[p+1], s2=slist[p+2], s3=slist[p+3];
    float w0=wcsr[p], w1=wcsr[p+1], w2=wcsr[p+2], w3=wcsr[p+3];
    float x0=bfu2f(xw2b[(size_t)s0*128+c]), x1=bfu2f(xw2b[(size_t)s1*128+c]);
    float x2=bfu2f(xw2b[(size_t)s2*128+c]), x3=bfu2f(xw2b[(size_t)s3*128+c]);
    acc = fmaf(w0,x0,acc); acc = fmaf(w1,x1,acc); acc = fmaf(w2,x2,acc); acc = fmaf(w3,x3,acc);
  }
  for (; p<p1; ++p){
    int s = slist[p];
    acc = fmaf(wcsr[p], bfu2f(xw2b[(size_t)s*128+c]), acc);
  }
  out[(size_t)n*128+c] = acc/den2[n] + g2b[c];
}

extern "C" void kernel_launch(void* const* d_in, const int* in_sizes, int n_in,
                              void* d_out, int out_size, void* d_ws, size_t ws_size,
                              hipStream_t stream){
  const float* nodef  = (const float*)d_in[0];
  const float* poses  = (const float*)d_in[1];
  const float* pe_w1  = (const float*)d_in[2];
  const float* pe_b1  = (const float*)d_in[3];
  const float* pe_g1  = (const float*)d_in[4];
  const float* pe_be1 = (const float*)d_in[5];
  const float* pe_w2  = (const float*)d_in[6];
  const float* pe_b2  = (const float*)d_in[7];
  const float* pe_g2  = (const float*)d_in[8];
  const float* pe_be2 = (const float*)d_in[9];
  const float* gamma_w= (const float*)d_in[10];
  const float* gamma_b= (const float*)d_in[11];
  const float* beta_w = (const float*)d_in[12];
  const float* beta_b = (const float*)d_in[13];
  const float* g1_w   = (const float*)d_in[14];
  const float* g1_as  = (const float*)d_in[15];
  const float* g1_ad  = (const float*)d_in[16];
  const float* g1_b   = (const float*)d_in[17];
  const float* g2_w   = (const float*)d_in[18];
  const float* g2_as  = (const float*)d_in[19];
  const float* g2_ad  = (const float*)d_in[20];
  const float* g2_b   = (const float*)d_in[21];
  const int*   eidx   = (const int*)d_in[22];
  const int* srcA = eidx;
  const int* dstA = eidx + EE;

  char* w = (char*)d_ws;
  const size_t MB = 1048576;
  u16*   aggH  = (u16*)(w + 0);
  u16*   h1    = (u16*)(w + 0);
  u16*   h1sel = (u16*)(w + 32*MB);
  u16*   h2b   = (u16*)(w + 40*MB);
  u16*   nodefb= (u16*)(w + 56*MB);
  u16*   nfselb= (u16*)(w + 72*MB);
  float* psum  = (float*)(w + 88*MB);
  float* psq   = (float*)(w + 90*MB);
  u16*   encb  = (u16*)(w + 128*MB);
  char* sm = w + 144*MB;
  size_t off = 0;
  auto alloc = [&](size_t b)->void*{ void* p = sm+off; off += (b+255)&~(size_t)255; return p; };
  u16* pe_w2t = (u16*)alloc(64*128*2);
  u16* gwt    = (u16*)alloc(128*128*2);
  u16* bwt    = (u16*)alloc(128*128*2);
  u16* g1wt   = (u16*)alloc(1024*128*2);
  u16* g2wt   = (u16*)alloc(128*1024*2);
  u16* vtb    = (u16*)alloc(16*128*2);
  float* part2 = (float*)alloc(32*256*4);
  float* als1  = (float*)alloc((size_t)NN*8*4);
  float* ald1  = (float*)alloc((size_t)NN*8*4);
  float* als2  = (float*)alloc((size_t)NN*4);
  float* ald2  = (float*)alloc((size_t)NN*4);
  float* wself1= (float*)alloc((size_t)NN*8*4);
  float* den1  = (float*)alloc((size_t)NN*8*4);
  float* wcsr1 = (float*)alloc((size_t)EE*8*4);
  float* wself2= (float*)alloc((size_t)NN*4);
  float* den2  = (float*)alloc((size_t)NN*4);
  float* wcsr2 = (float*)alloc((size_t)EE*4);
  u16*  xw2b   = (u16*)alloc((size_t)NN*128*2);
  int* lastE   = (int*)alloc((size_t)NN*4);
  int* deg     = (int*)alloc((size_t)NN*4);
  int* cursor  = (int*)alloc((size_t)NN*4);
  int* indptr  = (int*)alloc((size_t)(NN+1)*4);
  int* slist   = (int*)alloc((size_t)EE*4);
  int* bsum    = (int*)alloc(1024);
  float* stats = (float*)alloc(4096);
  float* sum1 = stats, *sq1 = stats+64;
  float* a1 = stats+384, *c1 = stats+448, *a2 = stats+512, *c2 = stats+640;

  hipMemsetAsync(stats, 0, 384*4, stream);
  hipMemsetAsync(deg, 0, (size_t)NN*4, stream);
  hipMemsetAsync(cursor, 0, (size_t)NN*4, stream);
  hipMemsetAsync(lastE, 0xFF, (size_t)NN*4, stream);

  // weight conversion + attention-vector precontraction
  k_cvtT<<<(64*128+255)/256,256,0,stream>>>(pe_w2, pe_w2t, 64, 128);
  k_cvtT<<<(128*128+255)/256,256,0,stream>>>(gamma_w, gwt, 128, 128);
  k_cvtT<<<(128*128+255)/256,256,0,stream>>>(beta_w, bwt, 128, 128);
  k_cvtT<<<(128*1024+255)/256,256,0,stream>>>(g1_w, g1wt, 128, 1024);
  k_cvtT<<<(1024*128+255)/256,256,0,stream>>>(g2_w, g2wt, 1024, 128);
  k_cvtn<<<NN*128/1024,256,0,stream>>>(nodef, nodefb);
  k_vprep<<<4,256,0,stream>>>(g1_w, g1_as, g1_ad, vtb);

  // edge-MLP stage 1 + BN1
  k_bn1_stats<<<256,256,0,stream>>>(poses, pe_w1, pe_b1, sum1, sq1);
  k_bn_fin<<<1,64,0,stream>>>(sum1, sq1, pe_g1, pe_be1, nullptr, a1, c1, 64);
  k_h1<<<65536,256,0,stream>>>(poses, pe_w1, pe_b1, a1, c1, h1);

  // BN2 stats via MFMA GEMM, atomic-free
  k_mm<2><<<dim3(4096,1),256,0,stream>>>(h1, pe_w2t, nullptr, 64, 64, 64, 0,
      nullptr, pe_b2, nullptr, psum, psq, nullptr, nullptr, nullptr, nullptr);
  k_red2<<<32,256,0,stream>>>(psum, psq, part2);
  k_bn_fin2<<<1,128,0,stream>>>(part2, pe_g2, pe_be2, pe_b2, a2, c2);

  // last-edge selection + CSR build
  k_lastdeg<<<1024,256,0,stream>>>(dstA, lastE, deg);
  k_blocksum<<<256,256,0,stream>>>(deg, bsum);
  k_scanb<<<1,256,0,stream>>>(bsum);
  k_indptr<<<256,256,0,stream>>>(deg, bsum, indptr);
  k_fill<<<1024,256,0,stream>>>(srcA, dstA, indptr, cursor, slist);

  // fused selected-row gathers (h1sel + nfselb), then h2 GEMM with BN-ReLU epilogue
  k_gsel<<<4096,256,0,stream>>>(h1, nodefb, lastE, srcA, h1sel, nfselb);
  k_mm<6><<<dim3(1024,1),256,0,stream>>>(h1sel, pe_w2t, nullptr, 64, 64, 64, 128,
      h2b, a2, c2, nullptr, nullptr, nullptr, nullptr, nullptr, nullptr);

  // FiLM: fused gamma+beta GEMM with combine epilogue (coalesced nfsel) -> encb
  k_mm<7><<<dim3(1024,1),256,0,stream>>>(h2b, gwt, bwt, 128, 128, 128, 128,
      encb, nullptr, nullptr, nullptr, nullptr, gamma_b, beta_b, nfselb, lastE);

  // GAT1 attention logits via skinny MFMA + CSR softmax (no atomics)
  k_als1mm<<<1024,256,0,stream>>>(encb, vtb, als1, ald1);
  k_soft1<<<NN/4,256,0,stream>>>(slist, indptr, als1, ald1, wcsr1, den1, wself1);

  // single-pass enc aggregation (all 8 heads) -> aggH [N,1024]
  k_agg1<<<NN/4,256,0,stream>>>(encb, wcsr1, den1, wself1, slist, indptr, aggH);

  // fused GAT1 head projection + GAT2 GEMM (R3 geometry, 32x32 MFMA, grid 1024)
  k_proj<<<1024,512,0,stream>>>(aggH, g1wt, g2wt, g1_b, g2_as, g2_ad, xw2b, als2, ald2);

  // GAT2 softmax + aggregation
  k_soft2<<<NN/16,256,0,stream>>>(slist, indptr, als2, ald2, wcsr2, den2, wself2);
  k_gat2<<<NN,128,0,stream>>>(xw2b, wcsr2, den2, wself2, slist, indptr, g2_b, (float*)d_out);
}

// Round 7
// 435.090 us; speedup vs baseline: 1.0336x; 1.0336x over previous
//
#include <hip/hip_runtime.h>
#include <hip/hip_bf16.h>
#include <math.h>

#define NN 65536
#define EE 262144

typedef unsigned short u16;
typedef unsigned int u32;
typedef __attribute__((ext_vector_type(8))) short bf16x8;
typedef __attribute__((ext_vector_type(4))) float f32x4;

__device__ __forceinline__ float bfu2f(u16 u){ return __uint_as_float(((u32)u)<<16); }
__device__ __forceinline__ u16 f2bfu(float f){
  u32 x = __float_as_uint(f);
  return (u16)((x + 0x7fffu + ((x>>16)&1u)) >> 16);
}
__device__ __forceinline__ float lrelu(float x){ return x>0.f ? x : 0.2f*x; }
__device__ __forceinline__ float fexp(float x){ return __expf(x); }

// ---- weight convert + transpose: B [K][N] f32 -> Bt [N][K] bf16
__global__ void k_cvtT(const float* __restrict__ B, u16* __restrict__ Bt, int K, int N){
  int idx = blockIdx.x*256+threadIdx.x;
  if (idx < K*N){ int k = idx/N, n = idx - k*N; Bt[n*K+k] = f2bfu(B[idx]); }
}

// ---- node features f32 -> bf16 (vectorized)
__global__ void k_cvtn(const float* __restrict__ nf, u16* __restrict__ nfb){
  int i = (blockIdx.x*256+threadIdx.x)*4;
  float4 v = *(const float4*)(nf + i);
  ushort4 o; o.x=f2bfu(v.x); o.y=f2bfu(v.y); o.z=f2bfu(v.z); o.w=f2bfu(v.w);
  *(ushort4*)(nfb + i) = o;
}

// ---- BN1 stats over z1 = poses@w1+b1 (cols=64)
__global__ void k_bn1_stats(const float* __restrict__ poses, const float* __restrict__ w1,
                            const float* __restrict__ b1, float* __restrict__ sum1, float* __restrict__ sq1){
  int wave = (blockIdx.x*blockDim.x + threadIdx.x)>>6;
  int c = threadIdx.x & 63;
  float wc[6];
#pragma unroll
  for (int j=0;j<6;++j) wc[j] = w1[j*64+c];
  float bb = b1[c];
  float s=0.f,q=0.f;
  int e0 = wave*(EE/1024);
  for (int e=e0;e<e0+(EE/1024);++e){
    float z = bb;
#pragma unroll
    for (int j=0;j<6;++j) z = fmaf(poses[e*6+j], wc[j], z);
    s += z; q += z*z;
  }
  unsafeAtomicAdd(&sum1[c], s);
  unsafeAtomicAdd(&sq1[c], q);
}

__global__ void k_bn_fin(const float* __restrict__ sum, const float* __restrict__ sq,
                         const float* __restrict__ g, const float* __restrict__ be,
                         const float* __restrict__ bias0,
                         float* __restrict__ a, float* __restrict__ cc, int cols){
  int c = threadIdx.x;
  if (c<cols){
    float mu = sum[c]*(1.f/EE);
    float var = sq[c]*(1.f/EE) - mu*mu;
    float istd = rsqrtf(var + 1e-5f);
    float ac = istd*g[c];
    a[c] = ac;
    float cv = be[c] - mu*ac;
    if (bias0) cv += bias0[c]*ac;
    cc[c] = cv;
  }
}

// ---- reduce per-block BN2 partials: psum/psq [4096][128] -> part2 [32][256]
__global__ void k_red2(const float* __restrict__ psum, const float* __restrict__ psq,
                       float* __restrict__ part2){
  int t = threadIdx.x;
  int b0 = blockIdx.x*128;
  float s = 0.f;
  if (t < 128){
    for (int k=0;k<128;++k) s += psum[(size_t)(b0+k)*128 + t];
  } else {
    int c = t-128;
    for (int k=0;k<128;++k) s += psq[(size_t)(b0+k)*128 + c];
  }
  part2[blockIdx.x*256 + t] = s;
}

__global__ void k_bn_fin2(const float* __restrict__ part2,
                          const float* __restrict__ g, const float* __restrict__ be,
                          const float* __restrict__ bias0,
                          float* __restrict__ a, float* __restrict__ cc){
  int c = threadIdx.x;
  if (c<128){
    float s=0.f,q=0.f;
    for (int k=0;k<32;++k){ s += part2[k*256+c]; q += part2[k*256+128+c]; }
    float mu = s*(1.f/EE);
    float var = q*(1.f/EE) - mu*mu;
    float istd = rsqrtf(var + 1e-5f);
    float ac = istd*g[c];
    a[c] = ac;
    cc[c] = be[c] - mu*ac + bias0[c]*ac;
  }
}

// ---- h1 = relu(bn1(z1)) stored bf16 [E,64]
__global__ void k_h1(const float* __restrict__ poses, const float* __restrict__ w1, const float* __restrict__ b1,
                     const float* __restrict__ a1, const float* __restrict__ c1, u16* __restrict__ h1){
  int idx = blockIdx.x*256+threadIdx.x;
  int e = idx>>6, c = idx&63;
  float z = b1[c];
#pragma unroll
  for (int j=0;j<6;++j) z = fmaf(poses[e*6+j], w1[j*64+c], z);
  float h = z*a1[c]+c1[c];
  h1[idx] = f2bfu(h>0.f?h:0.f);
}

// ============ MFMA GEMM: C[64x128 tile] = A[M,K]bf16 @ Bt[N,K]bf16^T ============
// EPI: 2 BN partial stats | 6 relu(acc*a+c) bf16 | 7 fused gamma+beta FiLM (coalesced nfsel)
template<int EPI>
__launch_bounds__(256)
__global__ void k_mm(const u16* __restrict__ A, const u16* __restrict__ Bt,
                     const u16* __restrict__ Bt2,
                     int K, int lda, int ldbt, int ldc,
                     u16* __restrict__ outb,
                     const float* __restrict__ bias, const float* __restrict__ bias2,
                     float* __restrict__ ssum, float* __restrict__ ssq,
                     const float* __restrict__ gb,
                     const float* __restrict__ bb, const u16* __restrict__ nfselb,
                     const int* __restrict__ lastE){
  const int m0 = blockIdx.x*64, n0 = blockIdx.y*128;
  const int t = threadIdx.x;
  const int lane = t & 63, wv = t>>6;
  const int wr = wv>>1, wc = wv&1;
  __shared__ u16 Als[64*64];
  __shared__ u16 Bls[128*64];
  __shared__ u16 B2ls[EPI==7 ? 128*64 : 8];
  __shared__ float epiS[128][2];
  __shared__ float epiD[128][2];
  f32x4 acc[2][4];
  f32x4 acc2[2][4];
#pragma unroll
  for (int i=0;i<2;++i)
#pragma unroll
    for (int j=0;j<4;++j){ acc[i][j] = (f32x4){0.f,0.f,0.f,0.f}; acc2[i][j] = (f32x4){0.f,0.f,0.f,0.f}; }

  for (int k0=0;k0<K;k0+=64){
    constexpr int NS = (EPI==7) ? 10 : 6;
#pragma unroll
    for (int c=0;c<NS;++c){
      int gc = c*256 + t;
      if (gc < 512){
        int row = gc>>3, ch = gc&7;
        int sw = ((row<<3)|ch) ^ (row&7);
        *(uint4*)(Als + sw*8) = *(const uint4*)(A + (size_t)(m0+row)*lda + k0 + ch*8);
      } else if (gc < 1536){
        int g2 = gc - 512;
        int row = g2>>3, ch = g2&7;
        int sw = ((row<<3)|ch) ^ (row&7);
        *(uint4*)(Bls + sw*8) = *(const uint4*)(Bt + (size_t)(n0+row)*ldbt + k0 + ch*8);
      } else if constexpr (EPI==7){
        int g2 = gc - 1536;
        int row = g2>>3, ch = g2&7;
        int sw = ((row<<3)|ch) ^ (row&7);
        *(uint4*)(B2ls + sw*8) = *(const uint4*)(Bt2 + (size_t)(n0+row)*ldbt + k0 + ch*8);
      }
    }
    __syncthreads();
#pragma unroll
    for (int kk=0;kk<2;++kk){
      bf16x8 af[2], bfr[4];
      int ch = kk*4 + (lane>>4);
#pragma unroll
      for (int i=0;i<2;++i){
        int row = wr*32 + i*16 + (lane&15);
        int sw = ((row<<3)|ch) ^ (row&7);
        af[i] = *(const bf16x8*)(Als + sw*8);
      }
#pragma unroll
      for (int j=0;j<4;++j){
        int rowb = wc*64 + j*16 + (lane&15);
        int swb = ((rowb<<3)|ch) ^ (rowb&7);
        bfr[j] = *(const bf16x8*)(Bls + swb*8);
      }
#pragma unroll
      for (int i=0;i<2;++i)
#pragma unroll
        for (int j=0;j<4;++j)
          acc[i][j] = __builtin_amdgcn_mfma_f32_16x16x32_bf16(af[i], bfr[j], acc[i][j], 0,0,0);
      if constexpr (EPI==7){
        bf16x8 bf2[4];
#pragma unroll
        for (int j=0;j<4;++j){
          int rowb = wc*64 + j*16 + (lane&15);
          int swb = ((rowb<<3)|ch) ^ (rowb&7);
          bf2[j] = *(const bf16x8*)(B2ls + swb*8);
        }
#pragma unroll
        for (int i=0;i<2;++i)
#pragma unroll
          for (int j=0;j<4;++j)
            acc2[i][j] = __builtin_amdgcn_mfma_f32_16x16x32_bf16(af[i], bf2[j], acc2[i][j], 0,0,0);
      }
    }
    __syncthreads();
  }

  int cbase = wc*64 + (lane&15);

  if constexpr (EPI==6){
    float av[4], cv[4];
#pragma unroll
    for (int j=0;j<4;++j){ av[j]=bias[cbase+j*16]; cv[j]=bias2[cbase+j*16]; }
#pragma unroll
    for (int i=0;i<2;++i)
#pragma unroll
      for (int r=0;r<4;++r){
        int row = m0 + wr*32 + i*16 + ((lane>>4)<<2) + r;
#pragma unroll
        for (int j=0;j<4;++j){
          float h = fmaf(acc[i][j][r], av[j], cv[j]);
          outb[(size_t)row*128 + cbase + j*16] = f2bfu(h>0.f?h:0.f);
        }
      }
  } else if constexpr (EPI==2){
    float bv[4];
#pragma unroll
    for (int j=0;j<4;++j) bv[j]=bias[cbase+j*16];
    float s[4]={0,0,0,0}, q[4]={0,0,0,0};
#pragma unroll
    for (int i=0;i<2;++i)
#pragma unroll
      for (int j=0;j<4;++j)
#pragma unroll
        for (int r=0;r<4;++r){ float z = acc[i][j][r]+bv[j]; s[j]+=z; q[j]+=z*z; }
#pragma unroll
    for (int j=0;j<4;++j){
      float ss=s[j], qq=q[j];
      ss += __shfl_xor(ss,16); ss += __shfl_xor(ss,32);
      qq += __shfl_xor(qq,16); qq += __shfl_xor(qq,32);
      if (lane<16){
        epiS[wc*64+j*16+lane][wr] = ss;
        epiD[wc*64+j*16+lane][wr] = qq;
      }
    }
    __syncthreads();
    if (t<128){
      ssum[(size_t)blockIdx.x*128 + t] = epiS[t][0]+epiS[t][1];
      ssq[(size_t)blockIdx.x*128 + t]  = epiD[t][0]+epiD[t][1];
    }
  } else if constexpr (EPI==7){
    float gbv[4], bbv[4];
#pragma unroll
    for (int j=0;j<4;++j){ gbv[j]=gb[cbase+j*16]; bbv[j]=bb[cbase+j*16]; }
#pragma unroll
    for (int i=0;i<2;++i)
#pragma unroll
      for (int r=0;r<4;++r){
        int n = m0 + wr*32 + i*16 + ((lane>>4)<<2) + r;
        int le = lastE[n];
#pragma unroll
        for (int j=0;j<4;++j){
          int c = cbase + j*16;
          float nv = bfu2f(nfselb[(size_t)n*128+c]);
          float res;
          if (le>=0){
            float gp = acc[i][j][r] + gbv[j];
            float gam = 2.f/(1.f+fexp(-gp));
            res = fmaf(gam, nv, acc2[i][j][r] + bbv[j]);
          } else res = nv;
          outb[(size_t)n*128+c] = f2bfu(res);
        }
      }
  }
}

// ============ fused GAT1 head-projection + GAT2 GEMM — R3 proven geometry + setprio ============
// R6 post-mortem: 32x32 MFMA B-fragment reads are a structural 4-way bank conflict
// (conflicts 1.05M -> 8.4M). Constraint surface now mapped: {4 independent blocks/CU
// (barrier coverage) x 8-chunk split-K swizzle (conflict-free) x 32-acc-reg/thread
// (no spill)} — R3 is the optimum of all three. This round: R3 byte-identical +
// s_setprio(1) around the MFMA clusters (T5): 4 blocks/CU drift out of phase at
// barriers, so an MFMA-phase wave can outrank staging-phase waves for issue.
__launch_bounds__(512)
__global__ void k_proj(const u16* __restrict__ aggH, const u16* __restrict__ g1wt,
                       const u16* __restrict__ g2wt, const float* __restrict__ g1b,
                       const float* __restrict__ asv, const float* __restrict__ adv,
                       u16* __restrict__ xw2b, float* __restrict__ als2, float* __restrict__ ald2){
  const int m0 = blockIdx.x*64;
  const int t = threadIdx.x, lane = t&63, wv = t>>6;
  const int wr = wv>>1, wc = wv&1;          // wr: 0..3 (16-row group), wc: 64-col half
  __shared__ u16 ATls[64*128];   // 16KB union: Als [64][64] (stage1, 8KB) / Tls [64][128] (stage2)
  __shared__ u16 Wls[128*64];    // 16KB: weight tile [128 N][64 K]
  __shared__ float epiS[64][2];
  __shared__ float epiD[64][2];
  const int cbase = wc*64 + (lane&15);
  f32x4 acc2[4];
#pragma unroll
  for (int j=0;j<4;++j) acc2[j] = (f32x4){0.f,0.f,0.f,0.f};

  for (int hh=0; hh<8; ++hh){
    f32x4 acc1[4];
#pragma unroll
    for (int j=0;j<4;++j) acc1[j] = (f32x4){0.f,0.f,0.f,0.f};

    // ---- stage 1: acc1 = aggH_hh[64x128] @ W1_hh^T[128x128], two K-chunks of 64
    for (int k0=0;k0<128;k0+=64){
#pragma unroll
      for (int c=0;c<3;++c){
        int gc = c*512 + t;
        if (gc < 512){
          int row = gc>>3, ch = gc&7;
          int sw = ((row<<3)|ch) ^ (row&7);
          *(uint4*)(ATls + sw*8) = *(const uint4*)(aggH + (size_t)(m0+row)*1024 + hh*128 + k0 + ch*8);
        } else {
          int g2 = gc - 512;
          int row = g2>>3, ch = g2&7;
          int sw = ((row<<3)|ch) ^ (row&7);
          *(uint4*)(Wls + sw*8) = *(const uint4*)(g1wt + (size_t)(hh*128+row)*128 + k0 + ch*8);
        }
      }
      __syncthreads();
      __builtin_amdgcn_s_setprio(1);
#pragma unroll
      for (int kk=0;kk<2;++kk){
        bf16x8 af, bfr[4];
        int ch = kk*4 + (lane>>4);
        {
          int row = wr*16 + (lane&15);
          int sw = ((row<<3)|ch) ^ (row&7);
          af = *(const bf16x8*)(ATls + sw*8);
        }
#pragma unroll
        for (int j=0;j<4;++j){
          int rowb = wc*64 + j*16 + (lane&15);
          int swb = ((rowb<<3)|ch) ^ (rowb&7);
          bfr[j] = *(const bf16x8*)(Wls + swb*8);
        }
#pragma unroll
        for (int j=0;j<4;++j)
          acc1[j] = __builtin_amdgcn_mfma_f32_16x16x32_bf16(af, bfr[j], acc1[j], 0,0,0);
      }
      __builtin_amdgcn_s_setprio(0);
      __syncthreads();   // Als/Wls reads complete -> ATls reusable as Tls
    }
    // ---- T = ELU(acc1 + b1) -> ATls as Tls [64][128], 16-chunk swizzle
    {
      float bv[4];
#pragma unroll
      for (int j=0;j<4;++j) bv[j] = g1b[hh*128 + cbase + j*16];
#pragma unroll
      for (int r=0;r<4;++r){
        int mrow = wr*16 + ((lane>>4)<<2) + r;
#pragma unroll
        for (int j=0;j<4;++j){
          int c = cbase + j*16;
          float v = acc1[j][r] + bv[j];
          v = v>0.f ? v : fexp(v)-1.f;
          int sw = ((mrow<<4)|(c>>3)) ^ (mrow&7);
          ATls[sw*8 + (c&7)] = f2bfu(v);
        }
      }
    }
    // ---- stage 2: acc2 += T[64x128] @ W2_hh^T[128x128], two K-chunks of 64
    for (int k0=0;k0<128;k0+=64){
#pragma unroll
      for (int c=0;c<2;++c){
        int g2 = c*512 + t;
        int row = g2>>3, ch = g2&7;
        int sw = ((row<<3)|ch) ^ (row&7);
        *(uint4*)(Wls + sw*8) = *(const uint4*)(g2wt + (size_t)row*1024 + hh*128 + k0 + ch*8);
      }
      __syncthreads();   // covers T-writes + W2 staging
      __builtin_amdgcn_s_setprio(1);
#pragma unroll
      for (int kk=0;kk<2;++kk){
        bf16x8 af, bfr[4];
        int ch = kk*4 + (lane>>4);
        int chk = (k0>>3) + ch;
        {
          int row = wr*16 + (lane&15);
          int sw = ((row<<4)|chk) ^ (row&7);
          af = *(const bf16x8*)(ATls + sw*8);
        }
#pragma unroll
        for (int j=0;j<4;++j){
          int rowb = wc*64 + j*16 + (lane&15);
          int swb = ((rowb<<3)|ch) ^ (rowb&7);
          bfr[j] = *(const bf16x8*)(Wls + swb*8);
        }
#pragma unroll
        for (int j=0;j<4;++j)
          acc2[j] = __builtin_amdgcn_mfma_f32_16x16x32_bf16(af, bfr[j], acc2[j], 0,0,0);
      }
      __builtin_amdgcn_s_setprio(0);
      __syncthreads();   // Tls/Wls reads done -> next head's staging safe
    }
  }
  // ---- epilogue: xw2b store + fused als2/ald2
  float av[4], dv[4];
#pragma unroll
  for (int j=0;j<4;++j){ av[j]=asv[cbase+j*16]; dv[j]=adv[cbase+j*16]; }
#pragma unroll
  for (int r=0;r<4;++r){
    int lr = wr*16 + ((lane>>4)<<2) + r;
    int row = m0 + lr;
    float s=0.f, d=0.f;
#pragma unroll
    for (int j=0;j<4;++j){
      float v = acc2[j][r];
      xw2b[(size_t)row*128 + cbase + j*16] = f2bfu(v);
      s = fmaf(v, av[j], s); d = fmaf(v, dv[j], d);
    }
#pragma unroll
    for (int o=1;o<16;o<<=1){ s += __shfl_xor(s,o); d += __shfl_xor(d,o); }
    if ((lane&15)==0){ epiS[lr][wc]=s; epiD[lr][wc]=d; }
  }
  __syncthreads();
  if (t<64){
    als2[m0+t] = epiS[t][0]+epiS[t][1];
    ald2[m0+t] = epiD[t][0]+epiD[t][1];
  }
}

// ---- last-edge-wins + degree (fused) + CSR build
__global__ void k_lastdeg(const int* __restrict__ dst, int* __restrict__ lastE, int* __restrict__ deg){
  int e = blockIdx.x*256+threadIdx.x;
  int d = dst[e];
  atomicMax(&lastE[d], e);
  atomicAdd(&deg[d], 1);
}
__global__ void k_blocksum(const int* __restrict__ deg, int* __restrict__ bsum){
  __shared__ int s[256];
  int t = threadIdx.x;
  s[t] = deg[blockIdx.x*256+t];
  __syncthreads();
  for (int o=128;o>0;o>>=1){ if (t<o) s[t]+=s[t+o]; __syncthreads(); }
  if (!t) bsum[blockIdx.x]=s[0];
}
__global__ void k_scanb(int* __restrict__ bsum){
  __shared__ int s[256];
  int t=threadIdx.x;
  s[t]=bsum[t]; __syncthreads();
  for (int o=1;o<256;o<<=1){
    int v = s[t];
    if (t>=o) v += s[t-o];
    __syncthreads(); s[t]=v; __syncthreads();
  }
  bsum[t] = t ? s[t-1] : 0;
}
__global__ void k_indptr(const int* __restrict__ deg, const int* __restrict__ bsum, int* __restrict__ indptr){
  __shared__ int s[256];
  int t=threadIdx.x; int g=blockIdx.x*256+t;
  int d = deg[g];
  s[t]=d; __syncthreads();
  for (int o=1;o<256;o<<=1){
    int v = s[t];
    if (t>=o) v += s[t-o];
    __syncthreads(); s[t]=v; __syncthreads();
  }
  indptr[g] = bsum[blockIdx.x] + s[t] - d;
  if (g==NN-1) indptr[NN]=EE;
}
__global__ void k_fill(const int* __restrict__ srcA, const int* __restrict__ dstA,
                       const int* __restrict__ indptr, int* __restrict__ cursor, int* __restrict__ slist){
  int e = blockIdx.x*256+threadIdx.x;
  int d = dstA[e];
  int p = atomicAdd(&cursor[d],1);
  slist[indptr[d]+p] = srcA[e];
}

// ---- fused gather: h1sel [N,64]b + nfselb [N,128]b in one pass over lastE/srcA
__global__ void k_gsel(const u16* __restrict__ h1, const u16* __restrict__ nodefb,
                       const int* __restrict__ lastE, const int* __restrict__ srcA,
                       u16* __restrict__ h1sel, u16* __restrict__ nfselb){
  int g = blockIdx.x*256+threadIdx.x;
  int n = g>>4, ch = g&15;
  int le = lastE[n];
  int src = (le>=0) ? srcA[le] : n;
  *(uint4*)(nfselb + (size_t)n*128 + ch*8) = *(const uint4*)(nodefb + (size_t)src*128 + ch*8);
  if (ch < 8){
    uint4 v = make_uint4(0,0,0,0);
    if (le>=0) v = *(const uint4*)(h1 + (size_t)le*64 + ch*8);
    *(uint4*)(h1sel + (size_t)n*64 + ch*8) = v;
  }
}

// ---- vas1/vad1 precontraction -> bf16 V^T [16][128]
__global__ void k_vprep(const float* __restrict__ g1w, const float* __restrict__ as_,
                        const float* __restrict__ ad_, u16* __restrict__ vtb){
  int gid = blockIdx.x*256+threadIdx.x;
  if (gid<1024){
    int h = gid>>7, k = gid&127;
    float s=0.f,d=0.f;
    for (int cc=0;cc<128;++cc){
      float wv = g1w[(size_t)k*1024 + h*128+cc];
      s=fmaf(wv,as_[h*128+cc],s); d=fmaf(wv,ad_[h*128+cc],d);
    }
    vtb[h*128+k] = f2bfu(s);
    vtb[(h+8)*128+k] = f2bfu(d);
  }
}

// ---- als1/ald1 [N,8] via skinny MFMA: [N,16] = encb @ V^T
__launch_bounds__(256)
__global__ void k_als1mm(const u16* __restrict__ encb, const u16* __restrict__ vtb,
                         float* __restrict__ als, float* __restrict__ ald){
  int t = threadIdx.x, lane = t&63, wv = t>>6;
  int m0 = blockIdx.x*64 + wv*16;
  f32x4 acc = (f32x4){0.f,0.f,0.f,0.f};
  const u16* arow = encb + (size_t)(m0 + (lane&15))*128;
  const u16* brow = vtb + (lane&15)*128;
  int ko = (lane>>4)*8;
#pragma unroll
  for (int k0=0;k0<128;k0+=32){
    bf16x8 af = *(const bf16x8*)(arow + k0 + ko);
    bf16x8 bf = *(const bf16x8*)(brow + k0 + ko);
    acc = __builtin_amdgcn_mfma_f32_16x16x32_bf16(af, bf, acc, 0,0,0);
  }
  int o = lane&15;
#pragma unroll
  for (int r=0;r<4;++r){
    int row = m0 + ((lane>>4)<<2) + r;
    if (o<8) als[(size_t)row*8+o] = acc[r];
    else     ald[(size_t)row*8+(o-8)] = acc[r];
  }
}

// ---- CSR node-parallel softmax, GAT1: 1 wave/node, lanes = 8 edges x 8 heads
__launch_bounds__(256)
__global__ void k_soft1(const int* __restrict__ slist, const int* __restrict__ indptr,
                        const float* __restrict__ als, const float* __restrict__ ald,
                        float* __restrict__ wcsr, float* __restrict__ den1, float* __restrict__ wself1){
  int t = threadIdx.x;
  int n = blockIdx.x*4 + (t>>6);
  int lane = t&63;
  int ei = lane>>3, h = lane&7;
  int p0 = indptr[n], p1 = indptr[n+1];
  float adh = ald[(size_t)n*8+h];
  float selfsc = lrelu(als[(size_t)n*8+h] + adh);
  float m = selfsc;
  for (int p=p0+ei; p<p1; p+=8){
    int s = slist[p];
    m = fmaxf(m, lrelu(als[(size_t)s*8+h] + adh));
  }
  m = fmaxf(m, __shfl_xor(m,8));
  m = fmaxf(m, __shfl_xor(m,16));
  m = fmaxf(m, __shfl_xor(m,32));
  float ws = fexp(selfsc - m);
  float den = (ei==0) ? ws : 0.f;
  for (int p=p0+ei; p<p1; p+=8){
    int s = slist[p];
    float w = fexp(lrelu(als[(size_t)s*8+h] + adh) - m);
    wcsr[(size_t)p*8+h] = w;
    den += w;
  }
  den += __shfl_xor(den,8);
  den += __shfl_xor(den,16);
  den += __shfl_xor(den,32);
  if (ei==0){
    den1[(size_t)n*8+h] = den;
    wself1[(size_t)n*8+h] = ws;
  }
}

// ---- CSR node-parallel softmax, GAT2: 16 lanes/node
__launch_bounds__(256)
__global__ void k_soft2(const int* __restrict__ slist, const int* __restrict__ indptr,
                        const float* __restrict__ als, const float* __restrict__ ald,
                        float* __restrict__ wcsr, float* __restrict__ den2, float* __restrict__ wself2){
  int t = threadIdx.x;
  int n = blockIdx.x*16 + (t>>4);
  int l = t&15;
  int p0 = indptr[n], p1 = indptr[n+1];
  float adh = ald[n];
  float selfsc = lrelu(als[n] + adh);
  float m = selfsc;
  for (int p=p0+l; p<p1; p+=16)
    m = fmaxf(m, lrelu(als[slist[p]] + adh));
  m = fmaxf(m, __shfl_xor(m,1));
  m = fmaxf(m, __shfl_xor(m,2));
  m = fmaxf(m, __shfl_xor(m,4));
  m = fmaxf(m, __shfl_xor(m,8));
  float ws = fexp(selfsc - m);
  float den = (l==0) ? ws : 0.f;
  for (int p=p0+l; p<p1; p+=16){
    float w = fexp(lrelu(als[slist[p]] + adh) - m);
    wcsr[p] = w;
    den += w;
  }
  den += __shfl_xor(den,1);
  den += __shfl_xor(den,2);
  den += __shfl_xor(den,4);
  den += __shfl_xor(den,8);
  if (l==0){ den2[n] = den; wself2[n] = ws; }
}

// ---- GAT1 enc-space aggregation, single pass, all 8 heads per enc-row load
__launch_bounds__(256)
__global__ void k_agg1(const u16* __restrict__ encb, const float* __restrict__ wcsr,
                       const float* __restrict__ den1, const float* __restrict__ wself1,
                       const int* __restrict__ slist, const int* __restrict__ indptr,
                       u16* __restrict__ aggH){
  int t = threadIdx.x;
  int n = blockIdx.x*4 + (t>>6);
  int lane = t&63;
  int c0 = lane*2;
  int p0 = indptr[n], p1 = indptr[n+1];
  float a0[8], a1[8];
  {
    ushort2 u = *(const ushort2*)(encb + (size_t)n*128 + c0);
    float x0 = bfu2f(u.x), x1 = bfu2f(u.y);
#pragma unroll
    for (int h=0;h<8;++h){
      float ws = wself1[(size_t)n*8 + h];
      a0[h] = ws*x0; a1[h] = ws*x1;
    }
  }
  for (int p=p0; p<p1; ++p){
    int s = slist[p];
    float4 w0 = *(const float4*)(wcsr + (size_t)p*8);
    float4 w1 = *(const float4*)(wcsr + (size_t)p*8 + 4);
    ushort2 u = *(const ushort2*)(encb + (size_t)s*128 + c0);
    float x0 = bfu2f(u.x), x1 = bfu2f(u.y);
    a0[0]=fmaf(w0.x,x0,a0[0]); a1[0]=fmaf(w0.x,x1,a1[0]);
    a0[1]=fmaf(w0.y,x0,a0[1]); a1[1]=fmaf(w0.y,x1,a1[1]);
    a0[2]=fmaf(w0.z,x0,a0[2]); a1[2]=fmaf(w0.z,x1,a1[2]);
    a0[3]=fmaf(w0.w,x0,a0[3]); a1[3]=fmaf(w0.w,x1,a1[3]);
    a0[4]=fmaf(w1.x,x0,a0[4]); a1[4]=fmaf(w1.x,x1,a1[4]);
    a0[5]=fmaf(w1.y,x0,a0[5]); a1[5]=fmaf(w1.y,x1,a1[5]);
    a0[6]=fmaf(w1.z,x0,a0[6]); a1[6]=fmaf(w1.z,x1,a1[6]);
    a0[7]=fmaf(w1.w,x0,a0[7]); a1[7]=fmaf(w1.w,x1,a1[7]);
  }
#pragma unroll
  for (int h=0;h<8;++h){
    float rr = 1.f/den1[(size_t)n*8 + h];
    u32 pk = (u32)f2bfu(a0[h]*rr) | ((u32)f2bfu(a1[h]*rr)<<16);
    *(u32*)(aggH + (size_t)n*1024 + h*128 + c0) = pk;
  }
}

// ---- GAT2 aggregation: pure weighted gather of bf16 xw2
__launch_bounds__(128)
__global__ void k_gat2(const u16* __restrict__ xw2b, const float* __restrict__ wcsr,
                       const float* __restrict__ den2, const float* __restrict__ wself2,
                       const int* __restrict__ slist, const int* __restrict__ indptr,
                       const float* __restrict__ g2b, float* __restrict__ out){
  int n = blockIdx.x, c = threadIdx.x;
  int p0 = indptr[n], p1 = indptr[n+1];
  float acc = wself2[n]*bfu2f(xw2b[(size_t)n*128+c]);
  int p = p0;
  for (; p+4<=p1; p+=4){
    int s0=slist[p], s1=slist[p+1], s2=slist[p+2], s3=slist[p+3];
    float w0=wcsr[p], w1=wcsr[p+1], w2=wcsr[p+2], w3=wcsr[p+3];
    float x0=bfu2f(xw2b[(size_t)s0*128+c]), x1=bfu2f(xw2b[(size_t)s1*128+c]);
    float x2=bfu2f(xw2b[(size_t)s2*128+c]), x3=bfu2f(xw2b[(size_t)s3*128+c]);
    acc = fmaf(w0,x0,acc); acc = fmaf(w1,x1,acc); acc = fmaf(w2,x2,acc); acc = fmaf(w3,x3,acc);
  }
  for (; p<p1; ++p){
    int s = slist[p];
    acc = fmaf(wcsr[p], bfu2f(xw2b[(size_t)s*128+c]), acc);
  }
  out[(size_t)n*128+c] = acc/den2[n] + g2b[c];
}

extern "C" void kernel_launch(void* const* d_in, const int* in_sizes, int n_in,
                              void* d_out, int out_size, void* d_ws, size_t ws_size,
                              hipStream_t stream){
  const float* nodef  = (const float*)d_in[0];
  const float* poses  = (const float*)d_in[1];
  const float* pe_w1  = (const float*)d_in[2];
  const float* pe_b1  = (const float*)d_in[3];
  const float* pe_g1  = (const float*)d_in[4];
  const float* pe_be1 = (const float*)d_in[5];
  const float* pe_w2  = (const float*)d_in[6];
  const float* pe_b2  = (const float*)d_in[7];
  const float* pe_g2  = (const float*)d_in[8];
  const float* pe_be2 = (const float*)d_in[9];
  const float* gamma_w= (const float*)d_in[10];
  const float* gamma_b= (const float*)d_in[11];
  const float* beta_w = (const float*)d_in[12];
  const float* beta_b = (const float*)d_in[13];
  const float* g1_w   = (const float*)d_in[14];
  const float* g1_as  = (const float*)d_in[15];
  const float* g1_ad  = (const float*)d_in[16];
  const float* g1_b   = (const float*)d_in[17];
  const float* g2_w   = (const float*)d_in[18];
  const float* g2_as  = (const float*)d_in[19];
  const float* g2_ad  = (const float*)d_in[20];
  const float* g2_b   = (const float*)d_in[21];
  const int*   eidx   = (const int*)d_in[22];
  const int* srcA = eidx;
  const int* dstA = eidx + EE;

  char* w = (char*)d_ws;
  const size_t MB = 1048576;
  u16*   aggH  = (u16*)(w + 0);
  u16*   h1    = (u16*)(w + 0);
  u16*   h1sel = (u16*)(w + 32*MB);
  u16*   h2b   = (u16*)(w + 40*MB);
  u16*   nodefb= (u16*)(w + 56*MB);
  u16*   nfselb= (u16*)(w + 72*MB);
  float* psum  = (float*)(w + 88*MB);
  float* psq   = (float*)(w + 90*MB);
  u16*   encb  = (u16*)(w + 128*MB);
  char* sm = w + 144*MB;
  size_t off = 0;
  auto alloc = [&](size_t b)->void*{ void* p = sm+off; off += (b+255)&~(size_t)255; return p; };
  u16* pe_w2t = (u16*)alloc(64*128*2);
  u16* gwt    = (u16*)alloc(128*128*2);
  u16* bwt    = (u16*)alloc(128*128*2);
  u16* g1wt   = (u16*)alloc(1024*128*2);
  u16* g2wt   = (u16*)alloc(128*1024*2);
  u16* vtb    = (u16*)alloc(16*128*2);
  float* part2 = (float*)alloc(32*256*4);
  float* als1  = (float*)alloc((size_t)NN*8*4);
  float* ald1  = (float*)alloc((size_t)NN*8*4);
  float* als2  = (float*)alloc((size_t)NN*4);
  float* ald2  = (float*)alloc((size_t)NN*4);
  float* wself1= (float*)alloc((size_t)NN*8*4);
  float* den1  = (float*)alloc((size_t)NN*8*4);
  float* wcsr1 = (float*)alloc((size_t)EE*8*4);
  float* wself2= (float*)alloc((size_t)NN*4);
  float* den2  = (float*)alloc((size_t)NN*4);
  float* wcsr2 = (float*)alloc((size_t)EE*4);
  u16*  xw2b   = (u16*)alloc((size_t)NN*128*2);
  int* lastE   = (int*)alloc((size_t)NN*4);
  int* deg     = (int*)alloc((size_t)NN*4);
  int* cursor  = (int*)alloc((size_t)NN*4);
  int* indptr  = (int*)alloc((size_t)(NN+1)*4);
  int* slist   = (int*)alloc((size_t)EE*4);
  int* bsum    = (int*)alloc(1024);
  float* stats = (float*)alloc(4096);
  float* sum1 = stats, *sq1 = stats+64;
  float* a1 = stats+384, *c1 = stats+448, *a2 = stats+512, *c2 = stats+640;

  hipMemsetAsync(stats, 0, 384*4, stream);
  hipMemsetAsync(deg, 0, (size_t)NN*4, stream);
  hipMemsetAsync(cursor, 0, (size_t)NN*4, stream);
  hipMemsetAsync(lastE, 0xFF, (size_t)NN*4, stream);

  // weight conversion + attention-vector precontraction
  k_cvtT<<<(64*128+255)/256,256,0,stream>>>(pe_w2, pe_w2t, 64, 128);
  k_cvtT<<<(128*128+255)/256,256,0,stream>>>(gamma_w, gwt, 128, 128);
  k_cvtT<<<(128*128+255)/256,256,0,stream>>>(beta_w, bwt, 128, 128);
  k_cvtT<<<(128*1024+255)/256,256,0,stream>>>(g1_w, g1wt, 128, 1024);
  k_cvtT<<<(1024*128+255)/256,256,0,stream>>>(g2_w, g2wt, 1024, 128);
  k_cvtn<<<NN*128/1024,256,0,stream>>>(nodef, nodefb);
  k_vprep<<<4,256,0,stream>>>(g1_w, g1_as, g1_ad, vtb);

  // edge-MLP stage 1 + BN1
  k_bn1_stats<<<256,256,0,stream>>>(poses, pe_w1, pe_b1, sum1, sq1);
  k_bn_fin<<<1,64,0,stream>>>(sum1, sq1, pe_g1, pe_be1, nullptr, a1, c1, 64);
  k_h1<<<65536,256,0,stream>>>(poses, pe_w1, pe_b1, a1, c1, h1);

  // BN2 stats via MFMA GEMM, atomic-free
  k_mm<2><<<dim3(4096,1),256,0,stream>>>(h1, pe_w2t, nullptr, 64, 64, 64, 0,
      nullptr, pe_b2, nullptr, psum, psq, nullptr, nullptr, nullptr, nullptr);
  k_red2<<<32,256,0,stream>>>(psum, psq, part2);
  k_bn_fin2<<<1,128,0,stream>>>(part2, pe_g2, pe_be2, pe_b2, a2, c2);

  // last-edge selection + CSR build
  k_lastdeg<<<1024,256,0,stream>>>(dstA, lastE, deg);
  k_blocksum<<<256,256,0,stream>>>(deg, bsum);
  k_scanb<<<1,256,0,stream>>>(bsum);
  k_indptr<<<256,256,0,stream>>>(deg, bsum, indptr);
  k_fill<<<1024,256,0,stream>>>(srcA, dstA, indptr, cursor, slist);

  // fused selected-row gathers (h1sel + nfselb), then h2 GEMM with BN-ReLU epilogue
  k_gsel<<<4096,256,0,stream>>>(h1, nodefb, lastE, srcA, h1sel, nfselb);
  k_mm<6><<<dim3(1024,1),256,0,stream>>>(h1sel, pe_w2t, nullptr, 64, 64, 64, 128,
      h2b, a2, c2, nullptr, nullptr, nullptr, nullptr, nullptr, nullptr);

  // FiLM: fused gamma+beta GEMM with combine epilogue (coalesced nfsel) -> encb
  k_mm<7><<<dim3(1024,1),256,0,stream>>>(h2b, gwt, bwt, 128, 128, 128, 128,
      encb, nullptr, nullptr, nullptr, nullptr, gamma_b, beta_b, nfselb, lastE);

  // GAT1 attention logits via skinny MFMA + CSR softmax (no atomics)
  k_als1mm<<<1024,256,0,stream>>>(encb, vtb, als1, ald1);
  k_soft1<<<NN/4,256,0,stream>>>(slist, indptr, als1, ald1, wcsr1, den1, wself1);

  // single-pass enc aggregation (all 8 heads) -> aggH [N,1024]
  k_agg1<<<NN/4,256,0,stream>>>(encb, wcsr1, den1, wself1, slist, indptr, aggH);

  // fused GAT1 head projection + GAT2 GEMM (R3 proven geometry + setprio, grid 1024)
  k_proj<<<1024,512,0,stream>>>(aggH, g1wt, g2wt, g1_b, g2_as, g2_ad, xw2b, als2, ald2);

  // GAT2 softmax + aggregation
  k_soft2<<<NN/16,256,0,stream>>>(slist, indptr, als2, ald2, wcsr2, den2, wself2);
  k_gat2<<<NN,128,0,stream>>>(xw2b, wcsr2, den2, wself2, slist, indptr, g2_b, (float*)d_out);
}

// Round 8
// 427.647 us; speedup vs baseline: 1.0516x; 1.0174x over previous
//
#include <hip/hip_runtime.h>
#include <hip/hip_bf16.h>
#include <math.h>

#define NN 65536
#define EE 262144

typedef unsigned short u16;
typedef unsigned int u32;
typedef __attribute__((ext_vector_type(8))) short bf16x8;
typedef __attribute__((ext_vector_type(4))) float f32x4;

__device__ __forceinline__ float bfu2f(u16 u){ return __uint_as_float(((u32)u)<<16); }
__device__ __forceinline__ u16 f2bfu(float f){
  u32 x = __float_as_uint(f);
  return (u16)((x + 0x7fffu + ((x>>16)&1u)) >> 16);
}
__device__ __forceinline__ float lrelu(float x){ return x>0.f ? x : 0.2f*x; }
__device__ __forceinline__ float fexp(float x){ return __expf(x); }

// ============ fused prologue: all input-only jobs in one dispatch ============
// blocks [0,8192): nodef f32->bf16 (vectorized x4)
// [8192,8224): pe_w2 transpose 64x128 | [8224,8288): gamma_w 128^2 | [8288,8352): beta_w
// [8352,8864): g1_w 128x1024 | [8864,9376): g2_w 1024x128 | [9376,9380): vprep
// [9380,9636): BN1 stats | [9636,10660): last-edge + degree atomics
__global__ void k_prep(const float* __restrict__ nodef, u16* __restrict__ nodefb,
                       const float* __restrict__ pe_w2, u16* __restrict__ pe_w2t,
                       const float* __restrict__ gamma_w, u16* __restrict__ gwt,
                       const float* __restrict__ beta_w, u16* __restrict__ bwt,
                       const float* __restrict__ g1_w, u16* __restrict__ g1wt,
                       const float* __restrict__ g2_w, u16* __restrict__ g2wt,
                       const float* __restrict__ g1_as, const float* __restrict__ g1_ad,
                       u16* __restrict__ vtb,
                       const float* __restrict__ poses, const float* __restrict__ pe_w1,
                       const float* __restrict__ pe_b1,
                       float* __restrict__ sum1, float* __restrict__ sq1,
                       const int* __restrict__ dstA, int* __restrict__ lastE, int* __restrict__ deg){
  int bid = blockIdx.x, t = threadIdx.x;
  if (bid < 8192){
    int i = (bid*256+t)*4;
    float4 v = *(const float4*)(nodef + i);
    ushort4 o; o.x=f2bfu(v.x); o.y=f2bfu(v.y); o.z=f2bfu(v.z); o.w=f2bfu(v.w);
    *(ushort4*)(nodefb + i) = o;
  } else if (bid < 8224){
    int idx = (bid-8192)*256+t;
    int k = idx>>7, n = idx&127;
    pe_w2t[n*64+k] = f2bfu(pe_w2[idx]);
  } else if (bid < 8288){
    int idx = (bid-8224)*256+t;
    int k = idx>>7, n = idx&127;
    gwt[n*128+k] = f2bfu(gamma_w[idx]);
  } else if (bid < 8352){
    int idx = (bid-8288)*256+t;
    int k = idx>>7, n = idx&127;
    bwt[n*128+k] = f2bfu(beta_w[idx]);
  } else if (bid < 8864){
    int idx = (bid-8352)*256+t;
    int k = idx>>10, n = idx&1023;
    g1wt[n*128+k] = f2bfu(g1_w[idx]);
  } else if (bid < 9376){
    int idx = (bid-8864)*256+t;
    int k = idx>>7, n = idx&127;
    g2wt[n*1024+k] = f2bfu(g2_w[idx]);
  } else if (bid < 9380){
    int gid = (bid-9376)*256+t;
    if (gid<1024){
      int h = gid>>7, k = gid&127;
      float s=0.f,d=0.f;
      for (int cc=0;cc<128;++cc){
        float wv = g1_w[(size_t)k*1024 + h*128+cc];
        s=fmaf(wv,g1_as[h*128+cc],s); d=fmaf(wv,g1_ad[h*128+cc],d);
      }
      vtb[h*128+k] = f2bfu(s);
      vtb[(h+8)*128+k] = f2bfu(d);
    }
  } else if (bid < 9636){
    int wave = ((bid-9380)*256 + t)>>6;
    int c = t & 63;
    float wc[6];
#pragma unroll
    for (int j=0;j<6;++j) wc[j] = pe_w1[j*64+c];
    float bb = pe_b1[c];
    float s=0.f,q=0.f;
    int e0 = wave*(EE/1024);
    for (int e=e0;e<e0+(EE/1024);++e){
      float z = bb;
#pragma unroll
      for (int j=0;j<6;++j) z = fmaf(poses[e*6+j], wc[j], z);
      s += z; q += z*z;
    }
    unsafeAtomicAdd(&sum1[c], s);
    unsafeAtomicAdd(&sq1[c], q);
  } else {
    int e = (bid-9636)*256+t;
    int d = dstA[e];
    atomicMax(&lastE[d], e);
    atomicAdd(&deg[d], 1);
  }
}

__global__ void k_bn_fin(const float* __restrict__ sum, const float* __restrict__ sq,
                         const float* __restrict__ g, const float* __restrict__ be,
                         const float* __restrict__ bias0,
                         float* __restrict__ a, float* __restrict__ cc, int cols){
  int c = threadIdx.x;
  if (c<cols){
    float mu = sum[c]*(1.f/EE);
    float var = sq[c]*(1.f/EE) - mu*mu;
    float istd = rsqrtf(var + 1e-5f);
    float ac = istd*g[c];
    a[c] = ac;
    float cv = be[c] - mu*ac;
    if (bias0) cv += bias0[c]*ac;
    cc[c] = cv;
  }
}

// ---- reduce per-block BN2 partials: psum/psq [4096][128] -> part2 [32][256]
__global__ void k_red2(const float* __restrict__ psum, const float* __restrict__ psq,
                       float* __restrict__ part2){
  int t = threadIdx.x;
  int b0 = blockIdx.x*128;
  float s = 0.f;
  if (t < 128){
    for (int k=0;k<128;++k) s += psum[(size_t)(b0+k)*128 + t];
  } else {
    int c = t-128;
    for (int k=0;k<128;++k) s += psq[(size_t)(b0+k)*128 + c];
  }
  part2[blockIdx.x*256 + t] = s;
}

__global__ void k_bn_fin2(const float* __restrict__ part2,
                          const float* __restrict__ g, const float* __restrict__ be,
                          const float* __restrict__ bias0,
                          float* __restrict__ a, float* __restrict__ cc){
  int c = threadIdx.x;
  if (c<128){
    float s=0.f,q=0.f;
    for (int k=0;k<32;++k){ s += part2[k*256+c]; q += part2[k*256+128+c]; }
    float mu = s*(1.f/EE);
    float var = q*(1.f/EE) - mu*mu;
    float istd = rsqrtf(var + 1e-5f);
    float ac = istd*g[c];
    a[c] = ac;
    cc[c] = be[c] - mu*ac + bias0[c]*ac;
  }
}

// ---- h1 = relu(bn1(z1)) stored bf16 [E,64] — 2 cols/thread, packed u32 stores
__global__ void k_h1(const float* __restrict__ poses, const float* __restrict__ w1, const float* __restrict__ b1,
                     const float* __restrict__ a1, const float* __restrict__ c1, u16* __restrict__ h1){
  int idx = blockIdx.x*256+threadIdx.x;
  int e = idx>>5, cp = (idx&31)*2;
  float z0 = b1[cp], z1 = b1[cp+1];
#pragma unroll
  for (int j=0;j<6;++j){
    float pv = poses[e*6+j];
    z0 = fmaf(pv, w1[j*64+cp], z0);
    z1 = fmaf(pv, w1[j*64+cp+1], z1);
  }
  float h0 = z0*a1[cp]+c1[cp];     h0 = h0>0.f?h0:0.f;
  float h1v = z1*a1[cp+1]+c1[cp+1]; h1v = h1v>0.f?h1v:0.f;
  *(u32*)(h1 + (size_t)e*64 + cp) = (u32)f2bfu(h0) | ((u32)f2bfu(h1v)<<16);
}

// ============ MFMA GEMM: C[64x128 tile] = A[M,K]bf16 @ Bt[N,K]bf16^T ============
// EPI: 2 BN partial stats | 6 relu(acc*a+c) bf16 | 7 fused gamma+beta FiLM (coalesced nfsel)
template<int EPI>
__launch_bounds__(256)
__global__ void k_mm(const u16* __restrict__ A, const u16* __restrict__ Bt,
                     const u16* __restrict__ Bt2,
                     int K, int lda, int ldbt, int ldc,
                     u16* __restrict__ outb,
                     const float* __restrict__ bias, const float* __restrict__ bias2,
                     float* __restrict__ ssum, float* __restrict__ ssq,
                     const float* __restrict__ gb,
                     const float* __restrict__ bb, const u16* __restrict__ nfselb,
                     const int* __restrict__ lastE){
  const int m0 = blockIdx.x*64, n0 = blockIdx.y*128;
  const int t = threadIdx.x;
  const int lane = t & 63, wv = t>>6;
  const int wr = wv>>1, wc = wv&1;
  __shared__ u16 Als[64*64];
  __shared__ u16 Bls[128*64];
  __shared__ u16 B2ls[EPI==7 ? 128*64 : 8];
  __shared__ float epiS[128][2];
  __shared__ float epiD[128][2];
  f32x4 acc[2][4];
  f32x4 acc2[2][4];
#pragma unroll
  for (int i=0;i<2;++i)
#pragma unroll
    for (int j=0;j<4;++j){ acc[i][j] = (f32x4){0.f,0.f,0.f,0.f}; acc2[i][j] = (f32x4){0.f,0.f,0.f,0.f}; }

  for (int k0=0;k0<K;k0+=64){
    constexpr int NS = (EPI==7) ? 10 : 6;
#pragma unroll
    for (int c=0;c<NS;++c){
      int gc = c*256 + t;
      if (gc < 512){
        int row = gc>>3, ch = gc&7;
        int sw = ((row<<3)|ch) ^ (row&7);
        *(uint4*)(Als + sw*8) = *(const uint4*)(A + (size_t)(m0+row)*lda + k0 + ch*8);
      } else if (gc < 1536){
        int g2 = gc - 512;
        int row = g2>>3, ch = g2&7;
        int sw = ((row<<3)|ch) ^ (row&7);
        *(uint4*)(Bls + sw*8) = *(const uint4*)(Bt + (size_t)(n0+row)*ldbt + k0 + ch*8);
      } else if constexpr (EPI==7){
        int g2 = gc - 1536;
        int row = g2>>3, ch = g2&7;
        int sw = ((row<<3)|ch) ^ (row&7);
        *(uint4*)(B2ls + sw*8) = *(const uint4*)(Bt2 + (size_t)(n0+row)*ldbt + k0 + ch*8);
      }
    }
    __syncthreads();
#pragma unroll
    for (int kk=0;kk<2;++kk){
      bf16x8 af[2], bfr[4];
      int ch = kk*4 + (lane>>4);
#pragma unroll
      for (int i=0;i<2;++i){
        int row = wr*32 + i*16 + (lane&15);
        int sw = ((row<<3)|ch) ^ (row&7);
        af[i] = *(const bf16x8*)(Als + sw*8);
      }
#pragma unroll
      for (int j=0;j<4;++j){
        int rowb = wc*64 + j*16 + (lane&15);
        int swb = ((rowb<<3)|ch) ^ (rowb&7);
        bfr[j] = *(const bf16x8*)(Bls + swb*8);
      }
#pragma unroll
      for (int i=0;i<2;++i)
#pragma unroll
        for (int j=0;j<4;++j)
          acc[i][j] = __builtin_amdgcn_mfma_f32_16x16x32_bf16(af[i], bfr[j], acc[i][j], 0,0,0);
      if constexpr (EPI==7){
        bf16x8 bf2[4];
#pragma unroll
        for (int j=0;j<4;++j){
          int rowb = wc*64 + j*16 + (lane&15);
          int swb = ((rowb<<3)|ch) ^ (rowb&7);
          bf2[j] = *(const bf16x8*)(B2ls + swb*8);
        }
#pragma unroll
        for (int i=0;i<2;++i)
#pragma unroll
          for (int j=0;j<4;++j)
            acc2[i][j] = __builtin_amdgcn_mfma_f32_16x16x32_bf16(af[i], bf2[j], acc2[i][j], 0,0,0);
      }
    }
    __syncthreads();
  }

  int cbase = wc*64 + (lane&15);

  if constexpr (EPI==6){
    float av[4], cv[4];
#pragma unroll
    for (int j=0;j<4;++j){ av[j]=bias[cbase+j*16]; cv[j]=bias2[cbase+j*16]; }
#pragma unroll
    for (int i=0;i<2;++i)
#pragma unroll
      for (int r=0;r<4;++r){
        int row = m0 + wr*32 + i*16 + ((lane>>4)<<2) + r;
#pragma unroll
        for (int j=0;j<4;++j){
          float h = fmaf(acc[i][j][r], av[j], cv[j]);
          outb[(size_t)row*128 + cbase + j*16] = f2bfu(h>0.f?h:0.f);
        }
      }
  } else if constexpr (EPI==2){
    float bv[4];
#pragma unroll
    for (int j=0;j<4;++j) bv[j]=bias[cbase+j*16];
    float s[4]={0,0,0,0}, q[4]={0,0,0,0};
#pragma unroll
    for (int i=0;i<2;++i)
#pragma unroll
      for (int j=0;j<4;++j)
#pragma unroll
        for (int r=0;r<4;++r){ float z = acc[i][j][r]+bv[j]; s[j]+=z; q[j]+=z*z; }
#pragma unroll
    for (int j=0;j<4;++j){
      float ss=s[j], qq=q[j];
      ss += __shfl_xor(ss,16); ss += __shfl_xor(ss,32);
      qq += __shfl_xor(qq,16); qq += __shfl_xor(qq,32);
      if (lane<16){
        epiS[wc*64+j*16+lane][wr] = ss;
        epiD[wc*64+j*16+lane][wr] = qq;
      }
    }
    __syncthreads();
    if (t<128){
      ssum[(size_t)blockIdx.x*128 + t] = epiS[t][0]+epiS[t][1];
      ssq[(size_t)blockIdx.x*128 + t]  = epiD[t][0]+epiD[t][1];
    }
  } else if constexpr (EPI==7){
    float gbv[4], bbv[4];
#pragma unroll
    for (int j=0;j<4;++j){ gbv[j]=gb[cbase+j*16]; bbv[j]=bb[cbase+j*16]; }
#pragma unroll
    for (int i=0;i<2;++i)
#pragma unroll
      for (int r=0;r<4;++r){
        int n = m0 + wr*32 + i*16 + ((lane>>4)<<2) + r;
        int le = lastE[n];
#pragma unroll
        for (int j=0;j<4;++j){
          int c = cbase + j*16;
          float nv = bfu2f(nfselb[(size_t)n*128+c]);
          float res;
          if (le>=0){
            float gp = acc[i][j][r] + gbv[j];
            float gam = 2.f/(1.f+fexp(-gp));
            res = fmaf(gam, nv, acc2[i][j][r] + bbv[j]);
          } else res = nv;
          outb[(size_t)n*128+c] = f2bfu(res);
        }
      }
  }
}

// ============ fused GAT1 head-projection + GAT2 GEMM — R3 proven geometry + setprio ============
// Constraint surface mapped over R1-R6: {4 independent blocks/CU (barrier coverage) x
// 8-chunk split-K swizzle (conflict-free) x 32-acc-reg/thread (no spill)} — this is the
// optimum; all four structural departures regressed. FROZEN.
__launch_bounds__(512)
__global__ void k_proj(const u16* __restrict__ aggH, const u16* __restrict__ g1wt,
                       const u16* __restrict__ g2wt, const float* __restrict__ g1b,
                       const float* __restrict__ asv, const float* __restrict__ adv,
                       u16* __restrict__ xw2b, float* __restrict__ als2, float* __restrict__ ald2){
  const int m0 = blockIdx.x*64;
  const int t = threadIdx.x, lane = t&63, wv = t>>6;
  const int wr = wv>>1, wc = wv&1;          // wr: 0..3 (16-row group), wc: 64-col half
  __shared__ u16 ATls[64*128];   // 16KB union: Als [64][64] (stage1, 8KB) / Tls [64][128] (stage2)
  __shared__ u16 Wls[128*64];    // 16KB: weight tile [128 N][64 K]
  __shared__ float epiS[64][2];
  __shared__ float epiD[64][2];
  const int cbase = wc*64 + (lane&15);
  f32x4 acc2[4];
#pragma unroll
  for (int j=0;j<4;++j) acc2[j] = (f32x4){0.f,0.f,0.f,0.f};

  for (int hh=0; hh<8; ++hh){
    f32x4 acc1[4];
#pragma unroll
    for (int j=0;j<4;++j) acc1[j] = (f32x4){0.f,0.f,0.f,0.f};

    // ---- stage 1: acc1 = aggH_hh[64x128] @ W1_hh^T[128x128], two K-chunks of 64
    for (int k0=0;k0<128;k0+=64){
#pragma unroll
      for (int c=0;c<3;++c){
        int gc = c*512 + t;
        if (gc < 512){
          int row = gc>>3, ch = gc&7;
          int sw = ((row<<3)|ch) ^ (row&7);
          *(uint4*)(ATls + sw*8) = *(const uint4*)(aggH + (size_t)(m0+row)*1024 + hh*128 + k0 + ch*8);
        } else {
          int g2 = gc - 512;
          int row = g2>>3, ch = g2&7;
          int sw = ((row<<3)|ch) ^ (row&7);
          *(uint4*)(Wls + sw*8) = *(const uint4*)(g1wt + (size_t)(hh*128+row)*128 + k0 + ch*8);
        }
      }
      __syncthreads();
      __builtin_amdgcn_s_setprio(1);
#pragma unroll
      for (int kk=0;kk<2;++kk){
        bf16x8 af, bfr[4];
        int ch = kk*4 + (lane>>4);
        {
          int row = wr*16 + (lane&15);
          int sw = ((row<<3)|ch) ^ (row&7);
          af = *(const bf16x8*)(ATls + sw*8);
        }
#pragma unroll
        for (int j=0;j<4;++j){
          int rowb = wc*64 + j*16 + (lane&15);
          int swb = ((rowb<<3)|ch) ^ (rowb&7);
          bfr[j] = *(const bf16x8*)(Wls + swb*8);
        }
#pragma unroll
        for (int j=0;j<4;++j)
          acc1[j] = __builtin_amdgcn_mfma_f32_16x16x32_bf16(af, bfr[j], acc1[j], 0,0,0);
      }
      __builtin_amdgcn_s_setprio(0);
      __syncthreads();   // Als/Wls reads complete -> ATls reusable as Tls
    }
    // ---- T = ELU(acc1 + b1) -> ATls as Tls [64][128], 16-chunk swizzle
    {
      float bv[4];
#pragma unroll
      for (int j=0;j<4;++j) bv[j] = g1b[hh*128 + cbase + j*16];
#pragma unroll
      for (int r=0;r<4;++r){
        int mrow = wr*16 + ((lane>>4)<<2) + r;
#pragma unroll
        for (int j=0;j<4;++j){
          int c = cbase + j*16;
          float v = acc1[j][r] + bv[j];
          v = v>0.f ? v : fexp(v)-1.f;
          int sw = ((mrow<<4)|(c>>3)) ^ (mrow&7);
          ATls[sw*8 + (c&7)] = f2bfu(v);
        }
      }
    }
    // ---- stage 2: acc2 += T[64x128] @ W2_hh^T[128x128], two K-chunks of 64
    for (int k0=0;k0<128;k0+=64){
#pragma unroll
      for (int c=0;c<2;++c){
        int g2 = c*512 + t;
        int row = g2>>3, ch = g2&7;
        int sw = ((row<<3)|ch) ^ (row&7);
        *(uint4*)(Wls + sw*8) = *(const uint4*)(g2wt + (size_t)row*1024 + hh*128 + k0 + ch*8);
      }
      __syncthreads();   // covers T-writes + W2 staging
      __builtin_amdgcn_s_setprio(1);
#pragma unroll
      for (int kk=0;kk<2;++kk){
        bf16x8 af, bfr[4];
        int ch = kk*4 + (lane>>4);
        int chk = (k0>>3) + ch;
        {
          int row = wr*16 + (lane&15);
          int sw = ((row<<4)|chk) ^ (row&7);
          af = *(const bf16x8*)(ATls + sw*8);
        }
#pragma unroll
        for (int j=0;j<4;++j){
          int rowb = wc*64 + j*16 + (lane&15);
          int swb = ((rowb<<3)|ch) ^ (rowb&7);
          bfr[j] = *(const bf16x8*)(Wls + swb*8);
        }
#pragma unroll
        for (int j=0;j<4;++j)
          acc2[j] = __builtin_amdgcn_mfma_f32_16x16x32_bf16(af, bfr[j], acc2[j], 0,0,0);
      }
      __builtin_amdgcn_s_setprio(0);
      __syncthreads();   // Tls/Wls reads done -> next head's staging safe
    }
  }
  // ---- epilogue: xw2b store + fused als2/ald2
  float av[4], dv[4];
#pragma unroll
  for (int j=0;j<4;++j){ av[j]=asv[cbase+j*16]; dv[j]=adv[cbase+j*16]; }
#pragma unroll
  for (int r=0;r<4;++r){
    int lr = wr*16 + ((lane>>4)<<2) + r;
    int row = m0 + lr;
    float s=0.f, d=0.f;
#pragma unroll
    for (int j=0;j<4;++j){
      float v = acc2[j][r];
      xw2b[(size_t)row*128 + cbase + j*16] = f2bfu(v);
      s = fmaf(v, av[j], s); d = fmaf(v, dv[j], d);
    }
#pragma unroll
    for (int o=1;o<16;o<<=1){ s += __shfl_xor(s,o); d += __shfl_xor(d,o); }
    if ((lane&15)==0){ epiS[lr][wc]=s; epiD[lr][wc]=d; }
  }
  __syncthreads();
  if (t<64){
    als2[m0+t] = epiS[t][0]+epiS[t][1];
    ald2[m0+t] = epiD[t][0]+epiD[t][1];
  }
}

// ---- CSR build (lastdeg folded into k_prep)
__global__ void k_blocksum(const int* __restrict__ deg, int* __restrict__ bsum){
  __shared__ int s[256];
  int t = threadIdx.x;
  s[t] = deg[blockIdx.x*256+t];
  __syncthreads();
  for (int o=128;o>0;o>>=1){ if (t<o) s[t]+=s[t+o]; __syncthreads(); }
  if (!t) bsum[blockIdx.x]=s[0];
}
__global__ void k_scanb(int* __restrict__ bsum){
  __shared__ int s[256];
  int t=threadIdx.x;
  s[t]=bsum[t]; __syncthreads();
  for (int o=1;o<256;o<<=1){
    int v = s[t];
    if (t>=o) v += s[t-o];
    __syncthreads(); s[t]=v; __syncthreads();
  }
  bsum[t] = t ? s[t-1] : 0;
}
__global__ void k_indptr(const int* __restrict__ deg, const int* __restrict__ bsum, int* __restrict__ indptr){
  __shared__ int s[256];
  int t=threadIdx.x; int g=blockIdx.x*256+t;
  int d = deg[g];
  s[t]=d; __syncthreads();
  for (int o=1;o<256;o<<=1){
    int v = s[t];
    if (t>=o) v += s[t-o];
    __syncthreads(); s[t]=v; __syncthreads();
  }
  indptr[g] = bsum[blockIdx.x] + s[t] - d;
  if (g==NN-1) indptr[NN]=EE;
}
__global__ void k_fill(const int* __restrict__ srcA, const int* __restrict__ dstA,
                       const int* __restrict__ indptr, int* __restrict__ cursor, int* __restrict__ slist){
  int e = blockIdx.x*256+threadIdx.x;
  int d = dstA[e];
  int p = atomicAdd(&cursor[d],1);
  slist[indptr[d]+p] = srcA[e];
}

// ---- fused gather: h1sel [N,64]b + nfselb [N,128]b in one pass over lastE/srcA
__global__ void k_gsel(const u16* __restrict__ h1, const u16* __restrict__ nodefb,
                       const int* __restrict__ lastE, const int* __restrict__ srcA,
                       u16* __restrict__ h1sel, u16* __restrict__ nfselb){
  int g = blockIdx.x*256+threadIdx.x;
  int n = g>>4, ch = g&15;
  int le = lastE[n];
  int src = (le>=0) ? srcA[le] : n;
  *(uint4*)(nfselb + (size_t)n*128 + ch*8) = *(const uint4*)(nodefb + (size_t)src*128 + ch*8);
  if (ch < 8){
    uint4 v = make_uint4(0,0,0,0);
    if (le>=0) v = *(const uint4*)(h1 + (size_t)le*64 + ch*8);
    *(uint4*)(h1sel + (size_t)n*64 + ch*8) = v;
  }
}

// ---- als1/ald1 [N,8] via skinny MFMA: [N,16] = encb @ V^T
__launch_bounds__(256)
__global__ void k_als1mm(const u16* __restrict__ encb, const u16* __restrict__ vtb,
                         float* __restrict__ als, float* __restrict__ ald){
  int t = threadIdx.x, lane = t&63, wv = t>>6;
  int m0 = blockIdx.x*64 + wv*16;
  f32x4 acc = (f32x4){0.f,0.f,0.f,0.f};
  const u16* arow = encb + (size_t)(m0 + (lane&15))*128;
  const u16* brow = vtb + (lane&15)*128;
  int ko = (lane>>4)*8;
#pragma unroll
  for (int k0=0;k0<128;k0+=32){
    bf16x8 af = *(const bf16x8*)(arow + k0 + ko);
    bf16x8 bf = *(const bf16x8*)(brow + k0 + ko);
    acc = __builtin_amdgcn_mfma_f32_16x16x32_bf16(af, bf, acc, 0,0,0);
  }
  int o = lane&15;
#pragma unroll
  for (int r=0;r<4;++r){
    int row = m0 + ((lane>>4)<<2) + r;
    if (o<8) als[(size_t)row*8+o] = acc[r];
    else     ald[(size_t)row*8+(o-8)] = acc[r];
  }
}

// ---- CSR node-parallel softmax, GAT1: 1 wave/node, lanes = 8 edges x 8 heads
__launch_bounds__(256)
__global__ void k_soft1(const int* __restrict__ slist, const int* __restrict__ indptr,
                        const float* __restrict__ als, const float* __restrict__ ald,
                        float* __restrict__ wcsr, float* __restrict__ den1, float* __restrict__ wself1){
  int t = threadIdx.x;
  int n = blockIdx.x*4 + (t>>6);
  int lane = t&63;
  int ei = lane>>3, h = lane&7;
  int p0 = indptr[n], p1 = indptr[n+1];
  float adh = ald[(size_t)n*8+h];
  float selfsc = lrelu(als[(size_t)n*8+h] + adh);
  float m = selfsc;
  for (int p=p0+ei; p<p1; p+=8){
    int s = slist[p];
    m = fmaxf(m, lrelu(als[(size_t)s*8+h] + adh));
  }
  m = fmaxf(m, __shfl_xor(m,8));
  m = fmaxf(m, __shfl_xor(m,16));
  m = fmaxf(m, __shfl_xor(m,32));
  float ws = fexp(selfsc - m);
  float den = (ei==0) ? ws : 0.f;
  for (int p=p0+ei; p<p1; p+=8){
    int s = slist[p];
    float w = fexp(lrelu(als[(size_t)s*8+h] + adh) - m);
    wcsr[(size_t)p*8+h] = w;
    den += w;
  }
  den += __shfl_xor(den,8);
  den += __shfl_xor(den,16);
  den += __shfl_xor(den,32);
  if (ei==0){
    den1[(size_t)n*8+h] = den;
    wself1[(size_t)n*8+h] = ws;
  }
}

// ---- CSR node-parallel softmax, GAT2: 16 lanes/node
__launch_bounds__(256)
__global__ void k_soft2(const int* __restrict__ slist, const int* __restrict__ indptr,
                        const float* __restrict__ als, const float* __restrict__ ald,
                        float* __restrict__ wcsr, float* __restrict__ den2, float* __restrict__ wself2){
  int t = threadIdx.x;
  int n = blockIdx.x*16 + (t>>4);
  int l = t&15;
  int p0 = indptr[n], p1 = indptr[n+1];
  float adh = ald[n];
  float selfsc = lrelu(als[n] + adh);
  float m = selfsc;
  for (int p=p0+l; p<p1; p+=16)
    m = fmaxf(m, lrelu(als[slist[p]] + adh));
  m = fmaxf(m, __shfl_xor(m,1));
  m = fmaxf(m, __shfl_xor(m,2));
  m = fmaxf(m, __shfl_xor(m,4));
  m = fmaxf(m, __shfl_xor(m,8));
  float ws = fexp(selfsc - m);
  float den = (l==0) ? ws : 0.f;
  for (int p=p0+l; p<p1; p+=16){
    float w = fexp(lrelu(als[slist[p]] + adh) - m);
    wcsr[p] = w;
    den += w;
  }
  den += __shfl_xor(den,1);
  den += __shfl_xor(den,2);
  den += __shfl_xor(den,4);
  den += __shfl_xor(den,8);
  if (l==0){ den2[n] = den; wself2[n] = ws; }
}

// ---- GAT1 enc-space aggregation, single pass, all 8 heads per enc-row load
__launch_bounds__(256)
__global__ void k_agg1(const u16* __restrict__ encb, const float* __restrict__ wcsr,
                       const float* __restrict__ den1, const float* __restrict__ wself1,
                       const int* __restrict__ slist, const int* __restrict__ indptr,
                       u16* __restrict__ aggH){
  int t = threadIdx.x;
  int n = blockIdx.x*4 + (t>>6);
  int lane = t&63;
  int c0 = lane*2;
  int p0 = indptr[n], p1 = indptr[n+1];
  float a0[8], a1[8];
  {
    ushort2 u = *(const ushort2*)(encb + (size_t)n*128 + c0);
    float x0 = bfu2f(u.x), x1 = bfu2f(u.y);
#pragma unroll
    for (int h=0;h<8;++h){
      float ws = wself1[(size_t)n*8 + h];
      a0[h] = ws*x0; a1[h] = ws*x1;
    }
  }
  for (int p=p0; p<p1; ++p){
    int s = slist[p];
    float4 w0 = *(const float4*)(wcsr + (size_t)p*8);
    float4 w1 = *(const float4*)(wcsr + (size_t)p*8 + 4);
    ushort2 u = *(const ushort2*)(encb + (size_t)s*128 + c0);
    float x0 = bfu2f(u.x), x1 = bfu2f(u.y);
    a0[0]=fmaf(w0.x,x0,a0[0]); a1[0]=fmaf(w0.x,x1,a1[0]);
    a0[1]=fmaf(w0.y,x0,a0[1]); a1[1]=fmaf(w0.y,x1,a1[1]);
    a0[2]=fmaf(w0.z,x0,a0[2]); a1[2]=fmaf(w0.z,x1,a1[2]);
    a0[3]=fmaf(w0.w,x0,a0[3]); a1[3]=fmaf(w0.w,x1,a1[3]);
    a0[4]=fmaf(w1.x,x0,a0[4]); a1[4]=fmaf(w1.x,x1,a1[4]);
    a0[5]=fmaf(w1.y,x0,a0[5]); a1[5]=fmaf(w1.y,x1,a1[5]);
    a0[6]=fmaf(w1.z,x0,a0[6]); a1[6]=fmaf(w1.z,x1,a1[6]);
    a0[7]=fmaf(w1.w,x0,a0[7]); a1[7]=fmaf(w1.w,x1,a1[7]);
  }
#pragma unroll
  for (int h=0;h<8;++h){
    float rr = 1.f/den1[(size_t)n*8 + h];
    u32 pk = (u32)f2bfu(a0[h]*rr) | ((u32)f2bfu(a1[h]*rr)<<16);
    *(u32*)(aggH + (size_t)n*1024 + h*128 + c0) = pk;
  }
}

// ---- GAT2 aggregation: wave-per-node, u32-paired bf16 gathers, float2 stores
__launch_bounds__(256)
__global__ void k_gat2(const u16* __restrict__ xw2b, const float* __restrict__ wcsr,
                       const float* __restrict__ den2, const float* __restrict__ wself2,
                       const int* __restrict__ slist, const int* __restrict__ indptr,
                       const float* __restrict__ g2b, float* __restrict__ out){
  int t = threadIdx.x;
  int n = blockIdx.x*4 + (t>>6);
  int c0 = (t&63)*2;
  int p0 = indptr[n], p1 = indptr[n+1];
  float ws = wself2[n];
  u32 u = *(const u32*)(xw2b + (size_t)n*128 + c0);
  float a0 = ws*bfu2f((u16)u), a1 = ws*bfu2f((u16)(u>>16));
  int p = p0;
  for (; p+2<=p1; p+=2){
    int s0=slist[p], s1=slist[p+1];
    float w0=wcsr[p], w1v=wcsr[p+1];
    u32 v0 = *(const u32*)(xw2b + (size_t)s0*128 + c0);
    u32 v1 = *(const u32*)(xw2b + (size_t)s1*128 + c0);
    a0 = fmaf(w0, bfu2f((u16)v0), a0);       a1 = fmaf(w0, bfu2f((u16)(v0>>16)), a1);
    a0 = fmaf(w1v, bfu2f((u16)v1), a0);      a1 = fmaf(w1v, bfu2f((u16)(v1>>16)), a1);
  }
  for (; p<p1; ++p){
    int s = slist[p];
    float w = wcsr[p];
    u32 v = *(const u32*)(xw2b + (size_t)s*128 + c0);
    a0 = fmaf(w, bfu2f((u16)v), a0);
    a1 = fmaf(w, bfu2f((u16)(v>>16)), a1);
  }
  float rr = 1.f/den2[n];
  float2 o;
  o.x = a0*rr + g2b[c0];
  o.y = a1*rr + g2b[c0+1];
  *(float2*)(out + (size_t)n*128 + c0) = o;
}

extern "C" void kernel_launch(void* const* d_in, const int* in_sizes, int n_in,
                              void* d_out, int out_size, void* d_ws, size_t ws_size,
                              hipStream_t stream){
  const float* nodef  = (const float*)d_in[0];
  const float* poses  = (const float*)d_in[1];
  const float* pe_w1  = (const float*)d_in[2];
  const float* pe_b1  = (const float*)d_in[3];
  const float* pe_g1  = (const float*)d_in[4];
  const float* pe_be1 = (const float*)d_in[5];
  const float* pe_w2  = (const float*)d_in[6];
  const float* pe_b2  = (const float*)d_in[7];
  const float* pe_g2  = (const float*)d_in[8];
  const float* pe_be2 = (const float*)d_in[9];
  const float* gamma_w= (const float*)d_in[10];
  const float* gamma_b= (const float*)d_in[11];
  const float* beta_w = (const float*)d_in[12];
  const float* beta_b = (const float*)d_in[13];
  const float* g1_w   = (const float*)d_in[14];
  const float* g1_as  = (const float*)d_in[15];
  const float* g1_ad  = (const float*)d_in[16];
  const float* g1_b   = (const float*)d_in[17];
  const float* g2_w   = (const float*)d_in[18];
  const float* g2_as  = (const float*)d_in[19];
  const float* g2_ad  = (const float*)d_in[20];
  const float* g2_b   = (const float*)d_in[21];
  const int*   eidx   = (const int*)d_in[22];
  const int* srcA = eidx;
  const int* dstA = eidx + EE;

  char* w = (char*)d_ws;
  const size_t MB = 1048576;
  u16*   aggH  = (u16*)(w + 0);
  u16*   h1    = (u16*)(w + 0);
  u16*   h1sel = (u16*)(w + 32*MB);
  u16*   h2b   = (u16*)(w + 40*MB);
  u16*   nodefb= (u16*)(w + 56*MB);
  u16*   nfselb= (u16*)(w + 72*MB);
  float* psum  = (float*)(w + 88*MB);
  float* psq   = (float*)(w + 90*MB);
  u16*   encb  = (u16*)(w + 128*MB);
  char* sm = w + 144*MB;
  size_t off = 0;
  auto alloc = [&](size_t b)->void*{ void* p = sm+off; off += (b+255)&~(size_t)255; return p; };
  u16* pe_w2t = (u16*)alloc(64*128*2);
  u16* gwt    = (u16*)alloc(128*128*2);
  u16* bwt    = (u16*)alloc(128*128*2);
  u16* g1wt   = (u16*)alloc(1024*128*2);
  u16* g2wt   = (u16*)alloc(128*1024*2);
  u16* vtb    = (u16*)alloc(16*128*2);
  float* part2 = (float*)alloc(32*256*4);
  float* als1  = (float*)alloc((size_t)NN*8*4);
  float* ald1  = (float*)alloc((size_t)NN*8*4);
  float* als2  = (float*)alloc((size_t)NN*4);
  float* ald2  = (float*)alloc((size_t)NN*4);
  float* wself1= (float*)alloc((size_t)NN*8*4);
  float* den1  = (float*)alloc((size_t)NN*8*4);
  float* wcsr1 = (float*)alloc((size_t)EE*8*4);
  float* wself2= (float*)alloc((size_t)NN*4);
  float* den2  = (float*)alloc((size_t)NN*4);
  float* wcsr2 = (float*)alloc((size_t)EE*4);
  u16*  xw2b   = (u16*)alloc((size_t)NN*128*2);
  int* lastE   = (int*)alloc((size_t)NN*4);
  int* deg     = (int*)alloc((size_t)NN*4);
  int* cursor  = (int*)alloc((size_t)NN*4);
  int* indptr  = (int*)alloc((size_t)(NN+1)*4);
  int* slist   = (int*)alloc((size_t)EE*4);
  int* bsum    = (int*)alloc(1024);
  float* stats = (float*)alloc(4096);
  float* sum1 = stats, *sq1 = stats+64;
  float* a1 = stats+384, *c1 = stats+448, *a2 = stats+512, *c2 = stats+640;

  hipMemsetAsync(stats, 0, 384*4, stream);
  hipMemsetAsync(deg, 0, (size_t)NN*4, stream);
  hipMemsetAsync(cursor, 0, (size_t)NN*4, stream);
  hipMemsetAsync(lastE, 0xFF, (size_t)NN*4, stream);

  // fused prologue: conversions + vprep + BN1 stats + last-edge/degree atomics
  k_prep<<<10660,256,0,stream>>>(nodef, nodefb, pe_w2, pe_w2t, gamma_w, gwt, beta_w, bwt,
                                 g1_w, g1wt, g2_w, g2wt, g1_as, g1_ad, vtb,
                                 poses, pe_w1, pe_b1, sum1, sq1, dstA, lastE, deg);

  // BN1 finalize + h1
  k_bn_fin<<<1,64,0,stream>>>(sum1, sq1, pe_g1, pe_be1, nullptr, a1, c1, 64);
  k_h1<<<32768,256,0,stream>>>(poses, pe_w1, pe_b1, a1, c1, h1);

  // BN2 stats via MFMA GEMM, atomic-free
  k_mm<2><<<dim3(4096,1),256,0,stream>>>(h1, pe_w2t, nullptr, 64, 64, 64, 0,
      nullptr, pe_b2, nullptr, psum, psq, nullptr, nullptr, nullptr, nullptr);
  k_red2<<<32,256,0,stream>>>(psum, psq, part2);
  k_bn_fin2<<<1,128,0,stream>>>(part2, pe_g2, pe_be2, pe_b2, a2, c2);

  // CSR build (lastdeg already done in k_prep)
  k_blocksum<<<256,256,0,stream>>>(deg, bsum);
  k_scanb<<<1,256,0,stream>>>(bsum);
  k_indptr<<<256,256,0,stream>>>(deg, bsum, indptr);
  k_fill<<<1024,256,0,stream>>>(srcA, dstA, indptr, cursor, slist);

  // fused selected-row gathers (h1sel + nfselb), then h2 GEMM with BN-ReLU epilogue
  k_gsel<<<4096,256,0,stream>>>(h1, nodefb, lastE, srcA, h1sel, nfselb);
  k_mm<6><<<dim3(1024,1),256,0,stream>>>(h1sel, pe_w2t, nullptr, 64, 64, 64, 128,
      h2b, a2, c2, nullptr, nullptr, nullptr, nullptr, nullptr, nullptr);

  // FiLM: fused gamma+beta GEMM with combine epilogue (coalesced nfsel) -> encb
  k_mm<7><<<dim3(1024,1),256,0,stream>>>(h2b, gwt, bwt, 128, 128, 128, 128,
      encb, nullptr, nullptr, nullptr, nullptr, gamma_b, beta_b, nfselb, lastE);

  // GAT1 attention logits via skinny MFMA + CSR softmax (no atomics)
  k_als1mm<<<1024,256,0,stream>>>(encb, vtb, als1, ald1);
  k_soft1<<<NN/4,256,0,stream>>>(slist, indptr, als1, ald1, wcsr1, den1, wself1);

  // single-pass enc aggregation (all 8 heads) -> aggH [N,1024]
  k_agg1<<<NN/4,256,0,stream>>>(encb, wcsr1, den1, wself1, slist, indptr, aggH);

  // fused GAT1 head projection + GAT2 GEMM (frozen R3 geometry + setprio)
  k_proj<<<1024,512,0,stream>>>(aggH, g1wt, g2wt, g1_b, g2_as, g2_ad, xw2b, als2, ald2);

  // GAT2 softmax + aggregation (wave-per-node)
  k_soft2<<<NN/16,256,0,stream>>>(slist, indptr, als2, ald2, wcsr2, den2, wself2);
  k_gat2<<<NN/4,256,0,stream>>>(xw2b, wcsr2, den2, wself2, slist, indptr, g2_b, (float*)d_out);
}

// Round 9
// 418.512 us; speedup vs baseline: 1.0746x; 1.0218x over previous
//
#include <hip/hip_runtime.h>
#include <hip/hip_bf16.h>
#include <math.h>

#define NN 65536
#define EE 262144

typedef unsigned short u16;
typedef unsigned int u32;
typedef __attribute__((ext_vector_type(8))) short bf16x8;
typedef __attribute__((ext_vector_type(4))) float f32x4;

__device__ __forceinline__ float bfu2f(u16 u){ return __uint_as_float(((u32)u)<<16); }
__device__ __forceinline__ u16 f2bfu(float f){
  u32 x = __float_as_uint(f);
  return (u16)((x + 0x7fffu + ((x>>16)&1u)) >> 16);
}
__device__ __forceinline__ float lrelu(float x){ return x>0.f ? x : 0.2f*x; }
__device__ __forceinline__ float fexp(float x){ return __expf(x); }

// ============ fused prologue: conversions + vprep + last-edge/degree ============
// blocks [0,8192): nodef f32->bf16 (vectorized x4)
// [8192,8224): pe_w2 transpose | [8224,8288): gamma_w | [8288,8352): beta_w
// [8352,8864): g1_w | [8864,9376): g2_w | [9376,9380): vprep
// [9380,10404): last-edge + degree atomics
__global__ void k_prep(const float* __restrict__ nodef, u16* __restrict__ nodefb,
                       const float* __restrict__ pe_w2, u16* __restrict__ pe_w2t,
                       const float* __restrict__ gamma_w, u16* __restrict__ gwt,
                       const float* __restrict__ beta_w, u16* __restrict__ bwt,
                       const float* __restrict__ g1_w, u16* __restrict__ g1wt,
                       const float* __restrict__ g2_w, u16* __restrict__ g2wt,
                       const float* __restrict__ g1_as, const float* __restrict__ g1_ad,
                       u16* __restrict__ vtb,
                       const int* __restrict__ dstA, int* __restrict__ lastE, int* __restrict__ deg){
  int bid = blockIdx.x, t = threadIdx.x;
  if (bid < 8192){
    int i = (bid*256+t)*4;
    float4 v = *(const float4*)(nodef + i);
    ushort4 o; o.x=f2bfu(v.x); o.y=f2bfu(v.y); o.z=f2bfu(v.z); o.w=f2bfu(v.w);
    *(ushort4*)(nodefb + i) = o;
  } else if (bid < 8224){
    int idx = (bid-8192)*256+t;
    int k = idx>>7, n = idx&127;
    pe_w2t[n*64+k] = f2bfu(pe_w2[idx]);
  } else if (bid < 8288){
    int idx = (bid-8224)*256+t;
    int k = idx>>7, n = idx&127;
    gwt[n*128+k] = f2bfu(gamma_w[idx]);
  } else if (bid < 8352){
    int idx = (bid-8288)*256+t;
    int k = idx>>7, n = idx&127;
    bwt[n*128+k] = f2bfu(beta_w[idx]);
  } else if (bid < 8864){
    int idx = (bid-8352)*256+t;
    int k = idx>>10, n = idx&1023;
    g1wt[n*128+k] = f2bfu(g1_w[idx]);
  } else if (bid < 9376){
    int idx = (bid-8864)*256+t;
    int k = idx>>7, n = idx&127;
    g2wt[n*1024+k] = f2bfu(g2_w[idx]);
  } else if (bid < 9380){
    int gid = (bid-9376)*256+t;
    if (gid<1024){
      int h = gid>>7, k = gid&127;
      float s=0.f,d=0.f;
      for (int cc=0;cc<128;++cc){
        float wv = g1_w[(size_t)k*1024 + h*128+cc];
        s=fmaf(wv,g1_as[h*128+cc],s); d=fmaf(wv,g1_ad[h*128+cc],d);
      }
      vtb[h*128+k] = f2bfu(s);
      vtb[(h+8)*128+k] = f2bfu(d);
    }
  } else {
    int e = (bid-9380)*256+t;
    int d = dstA[e];
    atomicMax(&lastE[d], e);
    atomicAdd(&deg[d], 1);
  }
}

// ---- BN1 stats, ATOMIC-FREE: per-block LDS reduce -> part1 [256][128]
// (R8 diagnosis: 131072 atomicAdds onto 512B of sum1/sq1 = L2 hot-line serialization)
__launch_bounds__(256)
__global__ void k_bn1p(const float* __restrict__ poses, const float* __restrict__ w1,
                       const float* __restrict__ b1, float* __restrict__ part1){
  int t = threadIdx.x;
  int wv = t>>6, c = t&63;
  int wave = blockIdx.x*4 + wv;
  float wc[6];
#pragma unroll
  for (int j=0;j<6;++j) wc[j] = w1[j*64+c];
  float bb = b1[c];
  float s=0.f,q=0.f;
  int e0 = wave*(EE/1024);
  for (int e=e0;e<e0+(EE/1024);++e){
    float z = bb;
#pragma unroll
    for (int j=0;j<6;++j) z = fmaf(poses[e*6+j], wc[j], z);
    s += z; q += z*z;
  }
  __shared__ float ls[4][64];
  __shared__ float lq[4][64];
  ls[wv][c]=s; lq[wv][c]=q;
  __syncthreads();
  if (t<64){
    float ss = ls[0][t]+ls[1][t]+ls[2][t]+ls[3][t];
    float qq = lq[0][t]+lq[1][t]+lq[2][t]+lq[3][t];
    part1[blockIdx.x*128 + t] = ss;
    part1[blockIdx.x*128 + 64 + t] = qq;
  }
}

__global__ void k_bn_fin1(const float* __restrict__ part1,
                          const float* __restrict__ g, const float* __restrict__ be,
                          float* __restrict__ a, float* __restrict__ cc){
  int c = threadIdx.x;
  if (c<64){
    float s=0.f,q=0.f;
    for (int k=0;k<256;++k){ s += part1[k*128+c]; q += part1[k*128+64+c]; }
    float mu = s*(1.f/EE);
    float var = q*(1.f/EE) - mu*mu;
    float istd = rsqrtf(var + 1e-5f);
    float ac = istd*g[c];
    a[c] = ac;
    cc[c] = be[c] - mu*ac;
  }
}

// ---- reduce per-block BN2 partials: psum/psq [4096][128] -> part2 [32][256]
__global__ void k_red2(const float* __restrict__ psum, const float* __restrict__ psq,
                       float* __restrict__ part2){
  int t = threadIdx.x;
  int b0 = blockIdx.x*128;
  float s = 0.f;
  if (t < 128){
    for (int k=0;k<128;++k) s += psum[(size_t)(b0+k)*128 + t];
  } else {
    int c = t-128;
    for (int k=0;k<128;++k) s += psq[(size_t)(b0+k)*128 + c];
  }
  part2[blockIdx.x*256 + t] = s;
}

__global__ void k_bn_fin2(const float* __restrict__ part2,
                          const float* __restrict__ g, const float* __restrict__ be,
                          const float* __restrict__ bias0,
                          float* __restrict__ a, float* __restrict__ cc){
  int c = threadIdx.x;
  if (c<128){
    float s=0.f,q=0.f;
    for (int k=0;k<32;++k){ s += part2[k*256+c]; q += part2[k*256+128+c]; }
    float mu = s*(1.f/EE);
    float var = q*(1.f/EE) - mu*mu;
    float istd = rsqrtf(var + 1e-5f);
    float ac = istd*g[c];
    a[c] = ac;
    cc[c] = be[c] - mu*ac + bias0[c]*ac;
  }
}

// ---- h1 = relu(bn1(z1)) stored bf16 [E,64] — 2 cols/thread, packed u32 stores
__global__ void k_h1(const float* __restrict__ poses, const float* __restrict__ w1, const float* __restrict__ b1,
                     const float* __restrict__ a1, const float* __restrict__ c1, u16* __restrict__ h1){
  int idx = blockIdx.x*256+threadIdx.x;
  int e = idx>>5, cp = (idx&31)*2;
  float z0 = b1[cp], z1 = b1[cp+1];
#pragma unroll
  for (int j=0;j<6;++j){
    float pv = poses[e*6+j];
    z0 = fmaf(pv, w1[j*64+cp], z0);
    z1 = fmaf(pv, w1[j*64+cp+1], z1);
  }
  float h0 = z0*a1[cp]+c1[cp];     h0 = h0>0.f?h0:0.f;
  float h1v = z1*a1[cp+1]+c1[cp+1]; h1v = h1v>0.f?h1v:0.f;
  *(u32*)(h1 + (size_t)e*64 + cp) = (u32)f2bfu(h0) | ((u32)f2bfu(h1v)<<16);
}

// ============ MFMA GEMM: C[64x128 tile] = A[M,K]bf16 @ Bt[N,K]bf16^T ============
// EPI: 2 BN partial stats | 6 relu(acc*a+c) bf16 | 7 fused gamma+beta FiLM (coalesced nfsel)
template<int EPI>
__launch_bounds__(256)
__global__ void k_mm(const u16* __restrict__ A, const u16* __restrict__ Bt,
                     const u16* __restrict__ Bt2,
                     int K, int lda, int ldbt, int ldc,
                     u16* __restrict__ outb,
                     const float* __restrict__ bias, const float* __restrict__ bias2,
                     float* __restrict__ ssum, float* __restrict__ ssq,
                     const float* __restrict__ gb,
                     const float* __restrict__ bb, const u16* __restrict__ nfselb,
                     const int* __restrict__ lastE){
  const int m0 = blockIdx.x*64, n0 = blockIdx.y*128;
  const int t = threadIdx.x;
  const int lane = t & 63, wv = t>>6;
  const int wr = wv>>1, wc = wv&1;
  __shared__ u16 Als[64*64];
  __shared__ u16 Bls[128*64];
  __shared__ u16 B2ls[EPI==7 ? 128*64 : 8];
  __shared__ float epiS[128][2];
  __shared__ float epiD[128][2];
  f32x4 acc[2][4];
  f32x4 acc2[2][4];
#pragma unroll
  for (int i=0;i<2;++i)
#pragma unroll
    for (int j=0;j<4;++j){ acc[i][j] = (f32x4){0.f,0.f,0.f,0.f}; acc2[i][j] = (f32x4){0.f,0.f,0.f,0.f}; }

  for (int k0=0;k0<K;k0+=64){
    constexpr int NS = (EPI==7) ? 10 : 6;
#pragma unroll
    for (int c=0;c<NS;++c){
      int gc = c*256 + t;
      if (gc < 512){
        int row = gc>>3, ch = gc&7;
        int sw = ((row<<3)|ch) ^ (row&7);
        *(uint4*)(Als + sw*8) = *(const uint4*)(A + (size_t)(m0+row)*lda + k0 + ch*8);
      } else if (gc < 1536){
        int g2 = gc - 512;
        int row = g2>>3, ch = g2&7;
        int sw = ((row<<3)|ch) ^ (row&7);
        *(uint4*)(Bls + sw*8) = *(const uint4*)(Bt + (size_t)(n0+row)*ldbt + k0 + ch*8);
      } else if constexpr (EPI==7){
        int g2 = gc - 1536;
        int row = g2>>3, ch = g2&7;
        int sw = ((row<<3)|ch) ^ (row&7);
        *(uint4*)(B2ls + sw*8) = *(const uint4*)(Bt2 + (size_t)(n0+row)*ldbt + k0 + ch*8);
      }
    }
    __syncthreads();
#pragma unroll
    for (int kk=0;kk<2;++kk){
      bf16x8 af[2], bfr[4];
      int ch = kk*4 + (lane>>4);
#pragma unroll
      for (int i=0;i<2;++i){
        int row = wr*32 + i*16 + (lane&15);
        int sw = ((row<<3)|ch) ^ (row&7);
        af[i] = *(const bf16x8*)(Als + sw*8);
      }
#pragma unroll
      for (int j=0;j<4;++j){
        int rowb = wc*64 + j*16 + (lane&15);
        int swb = ((rowb<<3)|ch) ^ (rowb&7);
        bfr[j] = *(const bf16x8*)(Bls + swb*8);
      }
#pragma unroll
      for (int i=0;i<2;++i)
#pragma unroll
        for (int j=0;j<4;++j)
          acc[i][j] = __builtin_amdgcn_mfma_f32_16x16x32_bf16(af[i], bfr[j], acc[i][j], 0,0,0);
      if constexpr (EPI==7){
        bf16x8 bf2[4];
#pragma unroll
        for (int j=0;j<4;++j){
          int rowb = wc*64 + j*16 + (lane&15);
          int swb = ((rowb<<3)|ch) ^ (rowb&7);
          bf2[j] = *(const bf16x8*)(B2ls + swb*8);
        }
#pragma unroll
        for (int i=0;i<2;++i)
#pragma unroll
          for (int j=0;j<4;++j)
            acc2[i][j] = __builtin_amdgcn_mfma_f32_16x16x32_bf16(af[i], bf2[j], acc2[i][j], 0,0,0);
      }
    }
    __syncthreads();
  }

  int cbase = wc*64 + (lane&15);

  if constexpr (EPI==6){
    float av[4], cv[4];
#pragma unroll
    for (int j=0;j<4;++j){ av[j]=bias[cbase+j*16]; cv[j]=bias2[cbase+j*16]; }
#pragma unroll
    for (int i=0;i<2;++i)
#pragma unroll
      for (int r=0;r<4;++r){
        int row = m0 + wr*32 + i*16 + ((lane>>4)<<2) + r;
#pragma unroll
        for (int j=0;j<4;++j){
          float h = fmaf(acc[i][j][r], av[j], cv[j]);
          outb[(size_t)row*128 + cbase + j*16] = f2bfu(h>0.f?h:0.f);
        }
      }
  } else if constexpr (EPI==2){
    float bv[4];
#pragma unroll
    for (int j=0;j<4;++j) bv[j]=bias[cbase+j*16];
    float s[4]={0,0,0,0}, q[4]={0,0,0,0};
#pragma unroll
    for (int i=0;i<2;++i)
#pragma unroll
      for (int j=0;j<4;++j)
#pragma unroll
        for (int r=0;r<4;++r){ float z = acc[i][j][r]+bv[j]; s[j]+=z; q[j]+=z*z; }
#pragma unroll
    for (int j=0;j<4;++j){
      float ss=s[j], qq=q[j];
      ss += __shfl_xor(ss,16); ss += __shfl_xor(ss,32);
      qq += __shfl_xor(qq,16); qq += __shfl_xor(qq,32);
      if (lane<16){
        epiS[wc*64+j*16+lane][wr] = ss;
        epiD[wc*64+j*16+lane][wr] = qq;
      }
    }
    __syncthreads();
    if (t<128){
      ssum[(size_t)blockIdx.x*128 + t] = epiS[t][0]+epiS[t][1];
      ssq[(size_t)blockIdx.x*128 + t]  = epiD[t][0]+epiD[t][1];
    }
  } else if constexpr (EPI==7){
    float gbv[4], bbv[4];
#pragma unroll
    for (int j=0;j<4;++j){ gbv[j]=gb[cbase+j*16]; bbv[j]=bb[cbase+j*16]; }
#pragma unroll
    for (int i=0;i<2;++i)
#pragma unroll
      for (int r=0;r<4;++r){
        int n = m0 + wr*32 + i*16 + ((lane>>4)<<2) + r;
        int le = lastE[n];
#pragma unroll
        for (int j=0;j<4;++j){
          int c = cbase + j*16;
          float nv = bfu2f(nfselb[(size_t)n*128+c]);
          float res;
          if (le>=0){
            float gp = acc[i][j][r] + gbv[j];
            float gam = 2.f/(1.f+fexp(-gp));
            res = fmaf(gam, nv, acc2[i][j][r] + bbv[j]);
          } else res = nv;
          outb[(size_t)n*128+c] = f2bfu(res);
        }
      }
  }
}

// ============ fused GAT1 head-projection + GAT2 GEMM — R3 proven geometry + setprio ============
// Constraint surface mapped over R1-R6: {4 independent blocks/CU (barrier coverage) x
// 8-chunk split-K swizzle (conflict-free) x 32-acc-reg/thread (no spill)} — FROZEN.
__launch_bounds__(512)
__global__ void k_proj(const u16* __restrict__ aggH, const u16* __restrict__ g1wt,
                       const u16* __restrict__ g2wt, const float* __restrict__ g1b,
                       const float* __restrict__ asv, const float* __restrict__ adv,
                       u16* __restrict__ xw2b, float* __restrict__ als2, float* __restrict__ ald2){
  const int m0 = blockIdx.x*64;
  const int t = threadIdx.x, lane = t&63, wv = t>>6;
  const int wr = wv>>1, wc = wv&1;
  __shared__ u16 ATls[64*128];
  __shared__ u16 Wls[128*64];
  __shared__ float epiS[64][2];
  __shared__ float epiD[64][2];
  const int cbase = wc*64 + (lane&15);
  f32x4 acc2[4];
#pragma unroll
  for (int j=0;j<4;++j) acc2[j] = (f32x4){0.f,0.f,0.f,0.f};

  for (int hh=0; hh<8; ++hh){
    f32x4 acc1[4];
#pragma unroll
    for (int j=0;j<4;++j) acc1[j] = (f32x4){0.f,0.f,0.f,0.f};

    for (int k0=0;k0<128;k0+=64){
#pragma unroll
      for (int c=0;c<3;++c){
        int gc = c*512 + t;
        if (gc < 512){
          int row = gc>>3, ch = gc&7;
          int sw = ((row<<3)|ch) ^ (row&7);
          *(uint4*)(ATls + sw*8) = *(const uint4*)(aggH + (size_t)(m0+row)*1024 + hh*128 + k0 + ch*8);
        } else {
          int g2 = gc - 512;
          int row = g2>>3, ch = g2&7;
          int sw = ((row<<3)|ch) ^ (row&7);
          *(uint4*)(Wls + sw*8) = *(const uint4*)(g1wt + (size_t)(hh*128+row)*128 + k0 + ch*8);
        }
      }
      __syncthreads();
      __builtin_amdgcn_s_setprio(1);
#pragma unroll
      for (int kk=0;kk<2;++kk){
        bf16x8 af, bfr[4];
        int ch = kk*4 + (lane>>4);
        {
          int row = wr*16 + (lane&15);
          int sw = ((row<<3)|ch) ^ (row&7);
          af = *(const bf16x8*)(ATls + sw*8);
        }
#pragma unroll
        for (int j=0;j<4;++j){
          int rowb = wc*64 + j*16 + (lane&15);
          int swb = ((rowb<<3)|ch) ^ (rowb&7);
          bfr[j] = *(const bf16x8*)(Wls + swb*8);
        }
#pragma unroll
        for (int j=0;j<4;++j)
          acc1[j] = __builtin_amdgcn_mfma_f32_16x16x32_bf16(af, bfr[j], acc1[j], 0,0,0);
      }
      __builtin_amdgcn_s_setprio(0);
      __syncthreads();
    }
    {
      float bv[4];
#pragma unroll
      for (int j=0;j<4;++j) bv[j] = g1b[hh*128 + cbase + j*16];
#pragma unroll
      for (int r=0;r<4;++r){
        int mrow = wr*16 + ((lane>>4)<<2) + r;
#pragma unroll
        for (int j=0;j<4;++j){
          int c = cbase + j*16;
          float v = acc1[j][r] + bv[j];
          v = v>0.f ? v : fexp(v)-1.f;
          int sw = ((mrow<<4)|(c>>3)) ^ (mrow&7);
          ATls[sw*8 + (c&7)] = f2bfu(v);
        }
      }
    }
    for (int k0=0;k0<128;k0+=64){
#pragma unroll
      for (int c=0;c<2;++c){
        int g2 = c*512 + t;
        int row = g2>>3, ch = g2&7;
        int sw = ((row<<3)|ch) ^ (row&7);
        *(uint4*)(Wls + sw*8) = *(const uint4*)(g2wt + (size_t)row*1024 + hh*128 + k0 + ch*8);
      }
      __syncthreads();
      __builtin_amdgcn_s_setprio(1);
#pragma unroll
      for (int kk=0;kk<2;++kk){
        bf16x8 af, bfr[4];
        int ch = kk*4 + (lane>>4);
        int chk = (k0>>3) + ch;
        {
          int row = wr*16 + (lane&15);
          int sw = ((row<<4)|chk) ^ (row&7);
          af = *(const bf16x8*)(ATls + sw*8);
        }
#pragma unroll
        for (int j=0;j<4;++j){
          int rowb = wc*64 + j*16 + (lane&15);
          int swb = ((rowb<<3)|ch) ^ (rowb&7);
          bfr[j] = *(const bf16x8*)(Wls + swb*8);
        }
#pragma unroll
        for (int j=0;j<4;++j)
          acc2[j] = __builtin_amdgcn_mfma_f32_16x16x32_bf16(af, bfr[j], acc2[j], 0,0,0);
      }
      __builtin_amdgcn_s_setprio(0);
      __syncthreads();
    }
  }
  float av[4], dv[4];
#pragma unroll
  for (int j=0;j<4;++j){ av[j]=asv[cbase+j*16]; dv[j]=adv[cbase+j*16]; }
#pragma unroll
  for (int r=0;r<4;++r){
    int lr = wr*16 + ((lane>>4)<<2) + r;
    int row = m0 + lr;
    float s=0.f, d=0.f;
#pragma unroll
    for (int j=0;j<4;++j){
      float v = acc2[j][r];
      xw2b[(size_t)row*128 + cbase + j*16] = f2bfu(v);
      s = fmaf(v, av[j], s); d = fmaf(v, dv[j], d);
    }
#pragma unroll
    for (int o=1;o<16;o<<=1){ s += __shfl_xor(s,o); d += __shfl_xor(d,o); }
    if ((lane&15)==0){ epiS[lr][wc]=s; epiD[lr][wc]=d; }
  }
  __syncthreads();
  if (t<64){
    als2[m0+t] = epiS[t][0]+epiS[t][1];
    ald2[m0+t] = epiD[t][0]+epiD[t][1];
  }
}

// ---- CSR build (lastdeg folded into k_prep)
__global__ void k_blocksum(const int* __restrict__ deg, int* __restrict__ bsum){
  __shared__ int s[256];
  int t = threadIdx.x;
  s[t] = deg[blockIdx.x*256+t];
  __syncthreads();
  for (int o=128;o>0;o>>=1){ if (t<o) s[t]+=s[t+o]; __syncthreads(); }
  if (!t) bsum[blockIdx.x]=s[0];
}
__global__ void k_scanb(int* __restrict__ bsum){
  __shared__ int s[256];
  int t=threadIdx.x;
  s[t]=bsum[t]; __syncthreads();
  for (int o=1;o<256;o<<=1){
    int v = s[t];
    if (t>=o) v += s[t-o];
    __syncthreads(); s[t]=v; __syncthreads();
  }
  bsum[t] = t ? s[t-1] : 0;
}
__global__ void k_indptr(const int* __restrict__ deg, const int* __restrict__ bsum, int* __restrict__ indptr){
  __shared__ int s[256];
  int t=threadIdx.x; int g=blockIdx.x*256+t;
  int d = deg[g];
  s[t]=d; __syncthreads();
  for (int o=1;o<256;o<<=1){
    int v = s[t];
    if (t>=o) v += s[t-o];
    __syncthreads(); s[t]=v; __syncthreads();
  }
  indptr[g] = bsum[blockIdx.x] + s[t] - d;
  if (g==NN-1) indptr[NN]=EE;
}
__global__ void k_fill(const int* __restrict__ srcA, const int* __restrict__ dstA,
                       const int* __restrict__ indptr, int* __restrict__ cursor, int* __restrict__ slist){
  int e = blockIdx.x*256+threadIdx.x;
  int d = dstA[e];
  int p = atomicAdd(&cursor[d],1);
  slist[indptr[d]+p] = srcA[e];
}

// ---- fused gather: h1sel [N,64]b + nfselb [N,128]b in one pass over lastE/srcA
__global__ void k_gsel(const u16* __restrict__ h1, const u16* __restrict__ nodefb,
                       const int* __restrict__ lastE, const int* __restrict__ srcA,
                       u16* __restrict__ h1sel, u16* __restrict__ nfselb){
  int g = blockIdx.x*256+threadIdx.x;
  int n = g>>4, ch = g&15;
  int le = lastE[n];
  int src = (le>=0) ? srcA[le] : n;
  *(uint4*)(nfselb + (size_t)n*128 + ch*8) = *(const uint4*)(nodefb + (size_t)src*128 + ch*8);
  if (ch < 8){
    uint4 v = make_uint4(0,0,0,0);
    if (le>=0) v = *(const uint4*)(h1 + (size_t)le*64 + ch*8);
    *(uint4*)(h1sel + (size_t)n*64 + ch*8) = v;
  }
}

// ---- als1/ald1 [N,8] via skinny MFMA: [N,16] = encb @ V^T
__launch_bounds__(256)
__global__ void k_als1mm(const u16* __restrict__ encb, const u16* __restrict__ vtb,
                         float* __restrict__ als, float* __restrict__ ald){
  int t = threadIdx.x, lane = t&63, wv = t>>6;
  int m0 = blockIdx.x*64 + wv*16;
  f32x4 acc = (f32x4){0.f,0.f,0.f,0.f};
  const u16* arow = encb + (size_t)(m0 + (lane&15))*128;
  const u16* brow = vtb + (lane&15)*128;
  int ko = (lane>>4)*8;
#pragma unroll
  for (int k0=0;k0<128;k0+=32){
    bf16x8 af = *(const bf16x8*)(arow + k0 + ko);
    bf16x8 bf = *(const bf16x8*)(brow + k0 + ko);
    acc = __builtin_amdgcn_mfma_f32_16x16x32_bf16(af, bf, acc, 0,0,0);
  }
  int o = lane&15;
#pragma unroll
  for (int r=0;r<4;++r){
    int row = m0 + ((lane>>4)<<2) + r;
    if (o<8) als[(size_t)row*8+o] = acc[r];
    else     ald[(size_t)row*8+(o-8)] = acc[r];
  }
}

// ---- CSR node-parallel softmax, GAT1: 1 wave/node, lanes = 8 edges x 8 heads
__launch_bounds__(256)
__global__ void k_soft1(const int* __restrict__ slist, const int* __restrict__ indptr,
                        const float* __restrict__ als, const float* __restrict__ ald,
                        float* __restrict__ wcsr, float* __restrict__ den1, float* __restrict__ wself1){
  int t = threadIdx.x;
  int n = blockIdx.x*4 + (t>>6);
  int lane = t&63;
  int ei = lane>>3, h = lane&7;
  int p0 = indptr[n], p1 = indptr[n+1];
  float adh = ald[(size_t)n*8+h];
  float selfsc = lrelu(als[(size_t)n*8+h] + adh);
  float m = selfsc;
  for (int p=p0+ei; p<p1; p+=8){
    int s = slist[p];
    m = fmaxf(m, lrelu(als[(size_t)s*8+h] + adh));
  }
  m = fmaxf(m, __shfl_xor(m,8));
  m = fmaxf(m, __shfl_xor(m,16));
  m = fmaxf(m, __shfl_xor(m,32));
  float ws = fexp(selfsc - m);
  float den = (ei==0) ? ws : 0.f;
  for (int p=p0+ei; p<p1; p+=8){
    int s = slist[p];
    float w = fexp(lrelu(als[(size_t)s*8+h] + adh) - m);
    wcsr[(size_t)p*8+h] = w;
    den += w;
  }
  den += __shfl_xor(den,8);
  den += __shfl_xor(den,16);
  den += __shfl_xor(den,32);
  if (ei==0){
    den1[(size_t)n*8+h] = den;
    wself1[(size_t)n*8+h] = ws;
  }
}

// ---- CSR node-parallel softmax, GAT2: 16 lanes/node
__launch_bounds__(256)
__global__ void k_soft2(const int* __restrict__ slist, const int* __restrict__ indptr,
                        const float* __restrict__ als, const float* __restrict__ ald,
                        float* __restrict__ wcsr, float* __restrict__ den2, float* __restrict__ wself2){
  int t = threadIdx.x;
  int n = blockIdx.x*16 + (t>>4);
  int l = t&15;
  int p0 = indptr[n], p1 = indptr[n+1];
  float adh = ald[n];
  float selfsc = lrelu(als[n] + adh);
  float m = selfsc;
  for (int p=p0+l; p<p1; p+=16)
    m = fmaxf(m, lrelu(als[slist[p]] + adh));
  m = fmaxf(m, __shfl_xor(m,1));
  m = fmaxf(m, __shfl_xor(m,2));
  m = fmaxf(m, __shfl_xor(m,4));
  m = fmaxf(m, __shfl_xor(m,8));
  float ws = fexp(selfsc - m);
  float den = (l==0) ? ws : 0.f;
  for (int p=p0+l; p<p1; p+=16){
    float w = fexp(lrelu(als[slist[p]] + adh) - m);
    wcsr[p] = w;
    den += w;
  }
  den += __shfl_xor(den,1);
  den += __shfl_xor(den,2);
  den += __shfl_xor(den,4);
  den += __shfl_xor(den,8);
  if (l==0){ den2[n] = den; wself2[n] = ws; }
}

// ---- GAT1 enc-space aggregation, single pass, all 8 heads per enc-row load
__launch_bounds__(256)
__global__ void k_agg1(const u16* __restrict__ encb, const float* __restrict__ wcsr,
                       const float* __restrict__ den1, const float* __restrict__ wself1,
                       const int* __restrict__ slist, const int* __restrict__ indptr,
                       u16* __restrict__ aggH){
  int t = threadIdx.x;
  int n = blockIdx.x*4 + (t>>6);
  int lane = t&63;
  int c0 = lane*2;
  int p0 = indptr[n], p1 = indptr[n+1];
  float a0[8], a1[8];
  {
    ushort2 u = *(const ushort2*)(encb + (size_t)n*128 + c0);
    float x0 = bfu2f(u.x), x1 = bfu2f(u.y);
#pragma unroll
    for (int h=0;h<8;++h){
      float ws = wself1[(size_t)n*8 + h];
      a0[h] = ws*x0; a1[h] = ws*x1;
    }
  }
  for (int p=p0; p<p1; ++p){
    int s = slist[p];
    float4 w0 = *(const float4*)(wcsr + (size_t)p*8);
    float4 w1 = *(const float4*)(wcsr + (size_t)p*8 + 4);
    ushort2 u = *(const ushort2*)(encb + (size_t)s*128 + c0);
    float x0 = bfu2f(u.x), x1 = bfu2f(u.y);
    a0[0]=fmaf(w0.x,x0,a0[0]); a1[0]=fmaf(w0.x,x1,a1[0]);
    a0[1]=fmaf(w0.y,x0,a0[1]); a1[1]=fmaf(w0.y,x1,a1[1]);
    a0[2]=fmaf(w0.z,x0,a0[2]); a1[2]=fmaf(w0.z,x1,a1[2]);
    a0[3]=fmaf(w0.w,x0,a0[3]); a1[3]=fmaf(w0.w,x1,a1[3]);
    a0[4]=fmaf(w1.x,x0,a0[4]); a1[4]=fmaf(w1.x,x1,a1[4]);
    a0[5]=fmaf(w1.y,x0,a0[5]); a1[5]=fmaf(w1.y,x1,a1[5]);
    a0[6]=fmaf(w1.z,x0,a0[6]); a1[6]=fmaf(w1.z,x1,a1[6]);
    a0[7]=fmaf(w1.w,x0,a0[7]); a1[7]=fmaf(w1.w,x1,a1[7]);
  }
#pragma unroll
  for (int h=0;h<8;++h){
    float rr = 1.f/den1[(size_t)n*8 + h];
    u32 pk = (u32)f2bfu(a0[h]*rr) | ((u32)f2bfu(a1[h]*rr)<<16);
    *(u32*)(aggH + (size_t)n*1024 + h*128 + c0) = pk;
  }
}

// ---- GAT2 aggregation: wave-per-node, u32-paired bf16 gathers, float2 stores
__launch_bounds__(256)
__global__ void k_gat2(const u16* __restrict__ xw2b, const float* __restrict__ wcsr,
                       const float* __restrict__ den2, const float* __restrict__ wself2,
                       const int* __restrict__ slist, const int* __restrict__ indptr,
                       const float* __restrict__ g2b, float* __restrict__ out){
  int t = threadIdx.x;
  int n = blockIdx.x*4 + (t>>6);
  int c0 = (t&63)*2;
  int p0 = indptr[n], p1 = indptr[n+1];
  float ws = wself2[n];
  u32 u = *(const u32*)(xw2b + (size_t)n*128 + c0);
  float a0 = ws*bfu2f((u16)u), a1 = ws*bfu2f((u16)(u>>16));
  int p = p0;
  for (; p+2<=p1; p+=2){
    int s0=slist[p], s1=slist[p+1];
    float w0=wcsr[p], w1v=wcsr[p+1];
    u32 v0 = *(const u32*)(xw2b + (size_t)s0*128 + c0);
    u32 v1 = *(const u32*)(xw2b + (size_t)s1*128 + c0);
    a0 = fmaf(w0, bfu2f((u16)v0), a0);       a1 = fmaf(w0, bfu2f((u16)(v0>>16)), a1);
    a0 = fmaf(w1v, bfu2f((u16)v1), a0);      a1 = fmaf(w1v, bfu2f((u16)(v1>>16)), a1);
  }
  for (; p<p1; ++p){
    int s = slist[p];
    float w = wcsr[p];
    u32 v = *(const u32*)(xw2b + (size_t)s*128 + c0);
    a0 = fmaf(w, bfu2f((u16)v), a0);
    a1 = fmaf(w, bfu2f((u16)(v>>16)), a1);
  }
  float rr = 1.f/den2[n];
  float2 o;
  o.x = a0*rr + g2b[c0];
  o.y = a1*rr + g2b[c0+1];
  *(float2*)(out + (size_t)n*128 + c0) = o;
}

extern "C" void kernel_launch(void* const* d_in, const int* in_sizes, int n_in,
                              void* d_out, int out_size, void* d_ws, size_t ws_size,
                              hipStream_t stream){
  const float* nodef  = (const float*)d_in[0];
  const float* poses  = (const float*)d_in[1];
  const float* pe_w1  = (const float*)d_in[2];
  const float* pe_b1  = (const float*)d_in[3];
  const float* pe_g1  = (const float*)d_in[4];
  const float* pe_be1 = (const float*)d_in[5];
  const float* pe_w2  = (const float*)d_in[6];
  const float* pe_b2  = (const float*)d_in[7];
  const float* pe_g2  = (const float*)d_in[8];
  const float* pe_be2 = (const float*)d_in[9];
  const float* gamma_w= (const float*)d_in[10];
  const float* gamma_b= (const float*)d_in[11];
  const float* beta_w = (const float*)d_in[12];
  const float* beta_b = (const float*)d_in[13];
  const float* g1_w   = (const float*)d_in[14];
  const float* g1_as  = (const float*)d_in[15];
  const float* g1_ad  = (const float*)d_in[16];
  const float* g1_b   = (const float*)d_in[17];
  const float* g2_w   = (const float*)d_in[18];
  const float* g2_as  = (const float*)d_in[19];
  const float* g2_ad  = (const float*)d_in[20];
  const float* g2_b   = (const float*)d_in[21];
  const int*   eidx   = (const int*)d_in[22];
  const int* srcA = eidx;
  const int* dstA = eidx + EE;

  char* w = (char*)d_ws;
  const size_t MB = 1048576;
  u16*   aggH  = (u16*)(w + 0);
  u16*   h1    = (u16*)(w + 0);
  u16*   h1sel = (u16*)(w + 32*MB);
  u16*   h2b   = (u16*)(w + 40*MB);
  u16*   nodefb= (u16*)(w + 56*MB);
  u16*   nfselb= (u16*)(w + 72*MB);
  float* psum  = (float*)(w + 88*MB);
  float* psq   = (float*)(w + 90*MB);
  u16*   encb  = (u16*)(w + 128*MB);
  char* sm = w + 144*MB;
  size_t off = 0;
  auto alloc = [&](size_t b)->void*{ void* p = sm+off; off += (b+255)&~(size_t)255; return p; };
  u16* pe_w2t = (u16*)alloc(64*128*2);
  u16* gwt    = (u16*)alloc(128*128*2);
  u16* bwt    = (u16*)alloc(128*128*2);
  u16* g1wt   = (u16*)alloc(1024*128*2);
  u16* g2wt   = (u16*)alloc(128*1024*2);
  u16* vtb    = (u16*)alloc(16*128*2);
  float* part2 = (float*)alloc(32*256*4);
  float* part1 = (float*)alloc(256*128*4);
  float* als1  = (float*)alloc((size_t)NN*8*4);
  float* ald1  = (float*)alloc((size_t)NN*8*4);
  float* als2  = (float*)alloc((size_t)NN*4);
  float* ald2  = (float*)alloc((size_t)NN*4);
  float* wself1= (float*)alloc((size_t)NN*8*4);
  float* den1  = (float*)alloc((size_t)NN*8*4);
  float* wcsr1 = (float*)alloc((size_t)EE*8*4);
  float* wself2= (float*)alloc((size_t)NN*4);
  float* den2  = (float*)alloc((size_t)NN*4);
  float* wcsr2 = (float*)alloc((size_t)EE*4);
  u16*  xw2b   = (u16*)alloc((size_t)NN*128*2);
  int* lastE   = (int*)alloc((size_t)NN*4);
  int* deg     = (int*)alloc((size_t)NN*4);
  int* cursor  = (int*)alloc((size_t)NN*4);
  int* indptr  = (int*)alloc((size_t)(NN+1)*4);
  int* slist   = (int*)alloc((size_t)EE*4);
  int* bsum    = (int*)alloc(1024);
  float* stats = (float*)alloc(4096);
  float* a1 = stats+384, *c1 = stats+448, *a2 = stats+512, *c2 = stats+640;

  hipMemsetAsync(deg, 0, (size_t)NN*4, stream);
  hipMemsetAsync(cursor, 0, (size_t)NN*4, stream);
  hipMemsetAsync(lastE, 0xFF, (size_t)NN*4, stream);

  // fused prologue: conversions + vprep + last-edge/degree atomics
  k_prep<<<10404,256,0,stream>>>(nodef, nodefb, pe_w2, pe_w2t, gamma_w, gwt, beta_w, bwt,
                                 g1_w, g1wt, g2_w, g2wt, g1_as, g1_ad, vtb,
                                 dstA, lastE, deg);

  // BN1 stats (atomic-free partials) + finalize + h1
  k_bn1p<<<256,256,0,stream>>>(poses, pe_w1, pe_b1, part1);
  k_bn_fin1<<<1,64,0,stream>>>(part1, pe_g1, pe_be1, a1, c1);
  k_h1<<<32768,256,0,stream>>>(poses, pe_w1, pe_b1, a1, c1, h1);

  // BN2 stats via MFMA GEMM, atomic-free
  k_mm<2><<<dim3(4096,1),256,0,stream>>>(h1, pe_w2t, nullptr, 64, 64, 64, 0,
      nullptr, pe_b2, nullptr, psum, psq, nullptr, nullptr, nullptr, nullptr);
  k_red2<<<32,256,0,stream>>>(psum, psq, part2);
  k_bn_fin2<<<1,128,0,stream>>>(part2, pe_g2, pe_be2, pe_b2, a2, c2);

  // CSR build (lastdeg already done in k_prep)
  k_blocksum<<<256,256,0,stream>>>(deg, bsum);
  k_scanb<<<1,256,0,stream>>>(bsum);
  k_indptr<<<256,256,0,stream>>>(deg, bsum, indptr);
  k_fill<<<1024,256,0,stream>>>(srcA, dstA, indptr, cursor, slist);

  // fused selected-row gathers (h1sel + nfselb), then h2 GEMM with BN-ReLU epilogue
  k_gsel<<<4096,256,0,stream>>>(h1, nodefb, lastE, srcA, h1sel, nfselb);
  k_mm<6><<<dim3(1024,1),256,0,stream>>>(h1sel, pe_w2t, nullptr, 64, 64, 64, 128,
      h2b, a2, c2, nullptr, nullptr, nullptr, nullptr, nullptr, nullptr);

  // FiLM: fused gamma+beta GEMM with combine epilogue (coalesced nfsel) -> encb
  k_mm<7><<<dim3(1024,1),256,0,stream>>>(h2b, gwt, bwt, 128, 128, 128, 128,
      encb, nullptr, nullptr, nullptr, nullptr, gamma_b, beta_b, nfselb, lastE);

  // GAT1 attention logits via skinny MFMA + CSR softmax (no atomics)
  k_als1mm<<<1024,256,0,stream>>>(encb, vtb, als1, ald1);
  k_soft1<<<NN/4,256,0,stream>>>(slist, indptr, als1, ald1, wcsr1, den1, wself1);

  // single-pass enc aggregation (all 8 heads) -> aggH [N,1024]
  k_agg1<<<NN/4,256,0,stream>>>(encb, wcsr1, den1, wself1, slist, indptr, aggH);

  // fused GAT1 head projection + GAT2 GEMM (frozen R3 geometry + setprio)
  k_proj<<<1024,512,0,stream>>>(aggH, g1wt, g2wt, g1_b, g2_as, g2_ad, xw2b, als2, ald2);

  // GAT2 softmax + aggregation (wave-per-node)
  k_soft2<<<NN/16,256,0,stream>>>(slist, indptr, als2, ald2, wcsr2, den2, wself2);
  k_gat2<<<NN/4,256,0,stream>>>(xw2b, wcsr2, den2, wself2, slist, indptr, g2_b, (float*)d_out);
}